// Round 3
// baseline (331.843 us; speedup 1.0000x reference)
//
#include <hip/hip_runtime.h>

typedef unsigned short ushort_t;
typedef unsigned int uint_t;

#define NB 4
#define NC 128
#define NH 128
#define NW 128
#define NPIX 65536   // NB*NH*NW
#define NMID 32
#define NKK 49
#define NK 392
#define NKP 400      // NK padded to 25 n-tiles of 16
#define NO 256
#define LN_EPS 1e-6f

typedef __attribute__((ext_vector_type(8))) short short8;
typedef __attribute__((ext_vector_type(4))) float floatx4;

__device__ __forceinline__ float bf2f(ushort_t u) {
    union { uint_t i; float f; } v; v.i = ((uint_t)u) << 16; return v.f;
}
__device__ __forceinline__ float bf2f_lo(uint_t u) {
    union { uint_t i; float f; } v; v.i = u << 16; return v.f;
}
__device__ __forceinline__ float bf2f_hi(uint_t u) {
    union { uint_t i; float f; } v; v.i = u & 0xffff0000u; return v.f;
}
__device__ __forceinline__ ushort_t f2bf(float f) {
    union { float f; uint_t i; } v; v.f = f;
    uint_t x = v.i;
    uint_t r = (x + 0x7FFFu + ((x >> 16) & 1u)) >> 16;
    return (ushort_t)r;
}
__device__ __forceinline__ float gelu_f(float x) {
    return 0.5f * x * (1.0f + erff(x * 0.70710678118654752f));
}
__device__ __forceinline__ float ldin(const void* p, int i, int isf32) {
    return isf32 ? ((const float*)p)[i] : bf2f(((const ushort_t*)p)[i]);
}
// global -> LDS direct DMA, 16B per lane; LDS dest = uniform base + lane*16
__device__ __forceinline__ void gload_lds16(const void* g, void* l) {
    __builtin_amdgcn_global_load_lds(
        (const __attribute__((address_space(1))) void*)g,
        (__attribute__((address_space(3))) void*)l, 16, 0, 0);
}

// ---------------------------------------------------------------------------
__global__ void kdetect(const uint_t* __restrict__ xw, int* __restrict__ flag) {
    int lane = threadIdx.x;
    int cnt = 0;
    for (int j = 0; j < 8; j++) {
        uint_t w = xw[lane * 8 + j];
        uint_t e = (w >> 7) & 0xffu;
        if (e >= 110u && e <= 135u) cnt++;
    }
    for (int d = 1; d < 64; d <<= 1) cnt += __shfl_xor(cnt, d);
    if (lane == 0) flag[0] = (cnt < 256) ? 1 : 0;
}

__global__ void ksentinel(uint_t* __restrict__ out, int nwords) {
    int i = blockIdx.x * 256 + threadIdx.x;
    if (i < nwords) out[i] = 0x40004000u;
}

// ---------------------------------------------------------------------------
// K0a: transpose x (B,C,H,W) -> xT (B,H,W,C) canonical bf16.
// ---------------------------------------------------------------------------
__global__ __launch_bounds__(256) void ktrans(const void* __restrict__ x,
                                              ushort_t* __restrict__ xT,
                                              const int* __restrict__ flag) {
    int isf32 = flag[0];
    int b = blockIdx.z, h = blockIdx.y;
    int wchunk = blockIdx.x & 1, cchunk = blockIdx.x >> 1;
    int w0 = wchunk << 6, c0 = cchunk << 5;
    __shared__ ushort_t tile[32][66];
    int tx = threadIdx.x & 63, ty = threadIdx.x >> 6;
    for (int r = 0; r < 32; r += 4) {
        int idx = (((b * NC + c0 + r + ty) * NH) + h) * NW + w0 + tx;
        tile[r + ty][tx] = isf32 ? f2bf(((const float*)x)[idx])
                                 : ((const ushort_t*)x)[idx];
    }
    __syncthreads();
    int cc = threadIdx.x & 31, wq = threadIdx.x >> 5;
    for (int pp = 0; pp < 64; pp += 8) {
        int wx = pp + wq;
        xT[((size_t)((b * NH + h) * NW) + w0 + wx) * NC + c0 + cc] = tile[cc][wx];
    }
}

// ---------------------------------------------------------------------------
// K0b: param prep (w1b/w2b for k1a; small vectors -> fp32).
// ---------------------------------------------------------------------------
__global__ __launch_bounds__(256) void kprep(const void* w1, const void* w2,
                                             const void* b1, const void* b2,
                                             const void* ln1w, const void* ln1b,
                                             const void* ln2w, const void* ln2b,
                                             const void* map_b,
                                             const void* ln3w, const void* ln3b,
                                             const int* __restrict__ flag,
                                             ushort_t* __restrict__ w1b,
                                             ushort_t* __restrict__ w2b,
                                             float* __restrict__ b1f,
                                             float* __restrict__ b2f,
                                             float* __restrict__ ln1wf,
                                             float* __restrict__ ln1bf,
                                             float* __restrict__ ln2wf,
                                             float* __restrict__ ln2bf,
                                             float* __restrict__ mbf,
                                             float* __restrict__ ln3wf,
                                             float* __restrict__ ln3bf) {
    int isf32 = flag[0];
    int i = blockIdx.x * 256 + threadIdx.x;
    if (i < NMID * NC) w1b[i] = f2bf(ldin(w1, i, isf32));
    if (i < NKP * NMID) w2b[i] = (i < NK * NMID) ? f2bf(ldin(w2, i, isf32))
                                                 : (ushort_t)0;
    if (i < NMID) b1f[i] = ldin(b1, i, isf32);
    if (i < NKP)  b2f[i] = (i < NK) ? ldin(b2, i, isf32) : 0.f;
    if (i < NC) { ln1wf[i] = ldin(ln1w, i, isf32); ln1bf[i] = ldin(ln1b, i, isf32); }
    if (i < NO) {
        ln2wf[i] = ldin(ln2w, i, isf32); ln2bf[i] = ldin(ln2b, i, isf32);
        mbf[i]   = ldin(map_b, i, isf32);
        ln3wf[i] = ldin(ln3w, i, isf32); ln3bf[i] = ldin(ln3b, i, isf32);
    }
}

// ---------------------------------------------------------------------------
// KFRAG: repack conv_w/map_w into k-block-major MFMA-fragment order for k23:
// chunk id cid = [kb:2][br:1][n4:4][lane:6], chunk = 8 bf16 = 16 B.
// Each kb-tile (2048 chunks = 32 KB) is CONTIGUOUS -> linear global_load_lds
// target in k23. o = n4*16 + (lane&15), ch = kb*32 + (lane>>4)*8 .. +8.
// grid 32 x 256.
// ---------------------------------------------------------------------------
__global__ __launch_bounds__(256) void kfrag(const void* conv_w, const void* map_w,
                                             const int* __restrict__ flag,
                                             ushort_t* __restrict__ wfrag) {
    int isf32 = flag[0];
    int cid = blockIdx.x * 256 + threadIdx.x;   // [0, 8192)
    int lane = cid & 63, n4 = (cid >> 6) & 15, br = (cid >> 10) & 1, kb = cid >> 11;
    int o = n4 * 16 + (lane & 15);
    int ch0 = kb * 32 + (lane >> 4) * 8;
    const void* src = br ? map_w : conv_w;
    ushort_t* dst = wfrag + (size_t)cid * 8;
#pragma unroll
    for (int j = 0; j < 8; j++)
        dst[j] = f2bf(ldin(src, o * NC + ch0 + j, isf32));
}

// ---------------------------------------------------------------------------
// K1a: wk producer (unchanged). grid 1024, block 256.
// ---------------------------------------------------------------------------
__global__ __launch_bounds__(256) void k1a(const ushort_t* __restrict__ xT,
                                           const ushort_t* __restrict__ w1b,
                                           const float* __restrict__ b1f,
                                           const ushort_t* __restrict__ w2b,
                                           const float* __restrict__ b2f,
                                           ushort_t* __restrict__ wkT) {
    __shared__ ushort_t midbuf[64 * 32];
    __shared__ ushort_t wkstage[NKP * 66];

    int t = threadIdx.x;
    int lane = t & 63;
    int w = __builtin_amdgcn_readfirstlane(t >> 6);
    int l16 = lane & 15, quad = lane >> 4;
    int tileid = blockIdx.x;
    int tilex = tileid & 15, tiley = (tileid >> 4) & 15, b = tileid >> 8;
    int h0 = tiley * 8, w0 = tilex * 8;

    int lpx_a = 16 * w + l16;
    int py = lpx_a >> 3, pxx = lpx_a & 7;
    const ushort_t* abase = xT + (size_t)((b * NH + h0 + py) * NW + w0 + pxx) * NC + quad * 8;
    floatx4 am0 = (floatx4)0.f, am1 = (floatx4)0.f;
#pragma unroll
    for (int kb = 0; kb < 4; kb++) {
        short8 a   = *(const short8*)(abase + kb * 32);
        short8 b0  = *(const short8*)(w1b + (l16) * NC + kb * 32 + quad * 8);
        short8 b1v = *(const short8*)(w1b + (16 + l16) * NC + kb * 32 + quad * 8);
        am0 = __builtin_amdgcn_mfma_f32_16x16x32_bf16(a, b0, am0, 0, 0, 0);
        am1 = __builtin_amdgcn_mfma_f32_16x16x32_bf16(a, b1v, am1, 0, 0, 0);
    }
    {
        float bia0 = b1f[l16], bia1 = b1f[16 + l16];
#pragma unroll
        for (int r = 0; r < 4; r++) {
            int m = 16 * w + quad * 4 + r;
            midbuf[m * 32 + l16]      = f2bf(fmaxf(am0[r] + bia0, 0.f));
            midbuf[m * 32 + 16 + l16] = f2bf(fmaxf(am1[r] + bia1, 0.f));
        }
    }
    __syncthreads();

    short8 aM = *(const short8*)(midbuf + (16 * w + l16) * 32 + quad * 8);
#pragma unroll
    for (int nt = 0; nt < 25; nt++) {
        int n = nt * 16 + l16;
        short8 bw = *(const short8*)(w2b + n * 32 + quad * 8);
        floatx4 c = __builtin_amdgcn_mfma_f32_16x16x32_bf16(aM, bw, (floatx4)0.f, 0, 0, 0);
        float bias = b2f[n];
#pragma unroll
        for (int r = 0; r < 4; r++)
            wkstage[n * 66 + 16 * w + quad * 4 + r] = f2bf(c[r] + bias);
    }
    __syncthreads();

    int krow = t >> 5, px2 = t & 31;
    for (int it = 0; it < 50; it++) {
        int k = it * 8 + krow;
        uint_t v = *(const uint_t*)&wkstage[k * 66 + 2 * px2];
        *(uint_t*)&wkT[(size_t)k * NPIX + tileid * 64 + 2 * px2] = v;
    }
}

// ---------------------------------------------------------------------------
// K1b v3 (unchanged from round 8). grid 1024, block 512.
// ---------------------------------------------------------------------------
__global__ __launch_bounds__(512) void k1b(const ushort_t* __restrict__ xT,
                                           const ushort_t* __restrict__ wkT,
                                           const float* __restrict__ ln1wf,
                                           const float* __restrict__ ln1bf,
                                           ushort_t* __restrict__ y1) {
    __shared__ __align__(16) char smem[50432];
    uint4* x8   = (uint4*)smem;
    float* sred = (float*)smem;

    int t = threadIdx.x;
    int lane = t & 63;
    int w = __builtin_amdgcn_readfirstlane(t >> 6);
    int tileid = blockIdx.x;
    int tilex = tileid & 15, tiley = (tileid >> 4) & 15, b = tileid >> 8;
    int h0 = tiley * 8, w0 = tilex * 8;
    int py = lane >> 3, pxx = lane & 7;

    const ushort_t* wkbase = wkT + (size_t)(w * NKK) * NPIX + tileid * 64 + lane;
    uint_t wkp[25];
#pragma unroll
    for (int j = 0; j < 24; j++) {
        uint_t lo = wkbase[(size_t)(2 * j) * NPIX];
        uint_t hi = wkbase[(size_t)(2 * j + 1) * NPIX];
        wkp[j] = lo | (hi << 16);
    }
    wkp[24] = wkbase[(size_t)48 * NPIX];

    for (int it = 0; it < 7; it++) {
        int idx = it * 512 + t;
        if (idx < 3136) {
            int oct = idx & 15, hp = idx >> 4;
            int hy = hp / 14, hx = hp - hy * 14;
            int gh = h0 + hy - 3, gw = w0 + hx - 3;
            uint4 v = make_uint4(0u, 0u, 0u, 0u);
            if ((unsigned)gh < (unsigned)NH && (unsigned)gw < (unsigned)NW) {
                v = *(const uint4*)&xT[(size_t)((b * NH + gh) * NW + gw) * NC + 8 * oct];
            }
            x8[oct * 197 + hp] = v;
        }
    }
    __syncthreads();

    int base0 = py * 14 + pxx;
    float a[16];
#pragma unroll
    for (int j = 0; j < 16; j++) a[j] = 0.f;

#pragma unroll
    for (int tap = 0; tap < NKK; tap++) {
        float wkf = (tap & 1) ? bf2f((ushort_t)(wkp[tap >> 1] >> 16))
                              : bf2f((ushort_t)(wkp[tap >> 1] & 0xffffu));
        int xa = base0 + (tap / 7) * 14 + (tap % 7);
        uint4 u0 = x8[(2 * w) * 197 + xa];
        uint4 u1 = x8[(2 * w + 1) * 197 + xa];
        a[0]  = fmaf(wkf, bf2f_lo(u0.x), a[0]);
        a[1]  = fmaf(wkf, bf2f_hi(u0.x), a[1]);
        a[2]  = fmaf(wkf, bf2f_lo(u0.y), a[2]);
        a[3]  = fmaf(wkf, bf2f_hi(u0.y), a[3]);
        a[4]  = fmaf(wkf, bf2f_lo(u0.z), a[4]);
        a[5]  = fmaf(wkf, bf2f_hi(u0.z), a[5]);
        a[6]  = fmaf(wkf, bf2f_lo(u0.w), a[6]);
        a[7]  = fmaf(wkf, bf2f_hi(u0.w), a[7]);
        a[8]  = fmaf(wkf, bf2f_lo(u1.x), a[8]);
        a[9]  = fmaf(wkf, bf2f_hi(u1.x), a[9]);
        a[10] = fmaf(wkf, bf2f_lo(u1.y), a[10]);
        a[11] = fmaf(wkf, bf2f_hi(u1.y), a[11]);
        a[12] = fmaf(wkf, bf2f_lo(u1.z), a[12]);
        a[13] = fmaf(wkf, bf2f_hi(u1.z), a[13]);
        a[14] = fmaf(wkf, bf2f_lo(u1.w), a[14]);
        a[15] = fmaf(wkf, bf2f_hi(u1.w), a[15]);
    }
    __syncthreads();

    float s = 0.f, sq = 0.f;
#pragma unroll
    for (int j = 0; j < 16; j++) { s += a[j]; sq += a[j] * a[j]; }
    sred[(w * 64 + lane) * 2]     = s;
    sred[(w * 64 + lane) * 2 + 1] = sq;
    __syncthreads();
    float ts = 0.f, tq = 0.f;
#pragma unroll
    for (int r = 0; r < 8; r++) {
        ts += sred[(r * 64 + lane) * 2];
        tq += sred[(r * 64 + lane) * 2 + 1];
    }
    float mean = ts * (1.0f / NC);
    float var = tq * (1.0f / NC) - mean * mean;
    float rstd = rsqrtf(var + LN_EPS);

    int p = (b * NH + h0 + py) * NW + w0 + pxx;
    uint_t pk[8];
#pragma unroll
    for (int j = 0; j < 8; j++) {
        int c0 = 16 * w + 2 * j;
        float g0 = gelu_f((a[2 * j] - mean) * rstd * ln1wf[c0] + ln1bf[c0]);
        float g1 = gelu_f((a[2 * j + 1] - mean) * rstd * ln1wf[c0 + 1] + ln1bf[c0 + 1]);
        pk[j] = (uint_t)f2bf(g0) | ((uint_t)f2bf(g1) << 16);
    }
    uint4* dst = (uint4*)(y1 + (size_t)p * NC + 16 * w);
    dst[0] = make_uint4(pk[0], pk[1], pk[2], pk[3]);
    dst[1] = make_uint4(pk[4], pk[5], pk[6], pk[7]);
}

// ---------------------------------------------------------------------------
// K1 fused fallback — used only if ws too small for wkT.
// ---------------------------------------------------------------------------
__global__ __launch_bounds__(64) void k1_fused(const ushort_t* __restrict__ xT,
                                               const ushort_t* __restrict__ w1b,
                                               const float* __restrict__ b1f,
                                               const ushort_t* __restrict__ w2b,
                                               const float* __restrict__ b2f,
                                               const float* __restrict__ ln1wf,
                                               const float* __restrict__ ln1bf,
                                               ushort_t* __restrict__ y1) {
    __shared__ ushort_t midbuf[16 * 32];
    __shared__ ushort_t wkbuf[16 * NKP];

    int lane = threadIdx.x;
    int l16 = lane & 15, quad = lane >> 4;
    int b = blockIdx.z;
    int h0 = blockIdx.y * 2, w0 = blockIdx.x * 8;

    int Pa = (b * NH + h0 + (l16 >> 3)) * NW + w0 + (l16 & 7);
    const ushort_t* abase = xT + (size_t)Pa * NC + quad * 8;
    floatx4 am0 = (floatx4)0.f, am1 = (floatx4)0.f;
#pragma unroll
    for (int kb = 0; kb < 4; kb++) {
        short8 a   = *(const short8*)(abase + kb * 32);
        short8 b0  = *(const short8*)(w1b + (l16) * NC + kb * 32 + quad * 8);
        short8 b1v = *(const short8*)(w1b + (16 + l16) * NC + kb * 32 + quad * 8);
        am0 = __builtin_amdgcn_mfma_f32_16x16x32_bf16(a, b0, am0, 0, 0, 0);
        am1 = __builtin_amdgcn_mfma_f32_16x16x32_bf16(a, b1v, am1, 0, 0, 0);
    }
    {
        float bia0 = b1f[l16], bia1 = b1f[16 + l16];
#pragma unroll
        for (int r = 0; r < 4; r++) {
            int m = quad * 4 + r;
            midbuf[m * 32 + l16]      = f2bf(fmaxf(am0[r] + bia0, 0.f));
            midbuf[m * 32 + 16 + l16] = f2bf(fmaxf(am1[r] + bia1, 0.f));
        }
    }
    __syncthreads();

    short8 aM = *(const short8*)(midbuf + l16 * 32 + quad * 8);
#pragma unroll
    for (int nt = 0; nt < 25; nt++) {
        int n = nt * 16 + l16;
        short8 bw = *(const short8*)(w2b + n * 32 + quad * 8);
        floatx4 c = __builtin_amdgcn_mfma_f32_16x16x32_bf16(aM, bw, (floatx4)0.f, 0, 0, 0);
        float bias = b2f[n];
#pragma unroll
        for (int r = 0; r < 4; r++)
            wkbuf[(quad * 4 + r) * NKP + n] = f2bf(c[r] + bias);
    }
    __syncthreads();

    int g = lane >> 3;
    float l1w0 = ln1wf[2 * lane], l1w1 = ln1wf[2 * lane + 1];
    float l1b0 = ln1bf[2 * lane], l1b1 = ln1bf[2 * lane + 1];

    for (int i = 0; i < 16; i++) {
        int hh0 = h0 + (i >> 3), ww0 = w0 + (i & 7);
        int p = (b * NH + hh0) * NW + ww0;
        const ushort_t* wkrow = wkbuf + i * NKP + g * NKK;
        float a0 = 0.f, a1 = 0.f;
#pragma unroll
        for (int dy = -3; dy <= 3; dy++) {
            int hh = hh0 + dy;
            if ((unsigned)hh >= (unsigned)NH) continue;
#pragma unroll
            for (int dx = -3; dx <= 3; dx++) {
                int ww = ww0 + dx;
                if ((unsigned)ww >= (unsigned)NW) continue;
                float wkv = bf2f(wkrow[(dy + 3) * 7 + (dx + 3)]);
                uint_t xp = *(const uint_t*)(xT + ((size_t)(p + dy * NW + dx)) * NC + 2 * lane);
                a0 = fmaf(wkv, bf2f((ushort_t)(xp & 0xffffu)), a0);
                a1 = fmaf(wkv, bf2f((ushort_t)(xp >> 16)), a1);
            }
        }
        float s = a0 + a1, sq = a0 * a0 + a1 * a1;
#pragma unroll
        for (int d = 1; d < 64; d <<= 1) {
            s  += __shfl_xor(s, d);
            sq += __shfl_xor(sq, d);
        }
        float mean = s * (1.0f / NC);
        float var = sq * (1.0f / NC) - mean * mean;
        float rstd = rsqrtf(var + LN_EPS);
        float g0 = gelu_f((a0 - mean) * rstd * l1w0 + l1b0);
        float g1 = gelu_f((a1 - mean) * rstd * l1w1 + l1b1);
        uint_t pk = (uint_t)f2bf(g0) | ((uint_t)f2bf(g1) << 16);
        *(uint_t*)(y1 + (size_t)p * NC + 2 * lane) = pk;
    }
}

// ---------------------------------------------------------------------------
// K23 v7: branch-split wave pairs for 2x occupancy. Block 256 = 2 pairs;
// even wave of a pair computes ONLY the conv branch (A=y1, br=0 frags, LN2),
// odd wave ONLY the map branch (A=xT, br=1 frags, +map bias, LN3) for the
// same 16 px. acc halves to 16 floatx4 = 64 regs -> __launch_bounds__(256,4)
// caps at 128 regs -> 4 waves/SIMD (was 2). Single 32KB LDS stage buffer
// (4 blocks/CU; cross-block TLP hides per-kb barriers). Each wave: own-branch
// LN stats (wave-internal butterfly), normalize in place, then pair-exchange
// HALF the normalized tiles through the dead stage buffer so both waves do
// 32 gelus + 8 stores (balanced). Math op-for-op identical to v6.
// grid 2048, block 256.
// ---------------------------------------------------------------------------
__global__ __launch_bounds__(256, 4) void k23(const ushort_t* __restrict__ y1,
                                              const ushort_t* __restrict__ xT,
                                              const ushort_t* __restrict__ wfrag,
                                              const float* __restrict__ mbf,
                                              const float* __restrict__ ln2wf,
                                              const float* __restrict__ ln2bf,
                                              const float* __restrict__ ln3wf,
                                              const float* __restrict__ ln3bf,
                                              void* __restrict__ out,
                                              const int* __restrict__ flag) {
    __shared__ __align__(16) char sbuf[32768];   // B stage, reused for exchange

    int isf32 = flag[0];
    int t = threadIdx.x;
    int lane = t & 63;
    int w = __builtin_amdgcn_readfirstlane(t >> 6);   // 0..3
    int quad = lane >> 4, l16 = lane & 15;
    int pair = w >> 1;                                // 0..1
    int isM  = w & 1;                                 // 0=conv(y1,LN2) 1=map(xT,LN3)

    int P0 = blockIdx.x * 32;
    int pw = P0 + pair * 16;                          // this pair's first pixel
    const ushort_t* Abase = (isM ? xT : y1) + (size_t)(pw + l16) * NC + quad * 8;

    // stage kb=0 B-tile (32KB): wave w covers chunks [w*512, w*512+512)
    {
        const ushort_t* gsrc = wfrag + (size_t)(w * 512 + lane) * 8;
        char* ldst = sbuf + (size_t)(w * 512) * 16;
#pragma unroll
        for (int i = 0; i < 8; i++)
            gload_lds16(gsrc + i * 64 * 8, ldst + i * 64 * 16);
    }
    // A operands for all 4 k-blocks (own branch only), hoisted to registers
    short8 Ar[4];
#pragma unroll
    for (int kb = 0; kb < 4; kb++) Ar[kb] = *(const short8*)(Abase + kb * 32);

    __syncthreads();

    floatx4 acc[16];
#pragma unroll
    for (int n4 = 0; n4 < 16; n4++) acc[n4] = (floatx4)0.f;

    const char* bbase = sbuf + isM * 16384;           // own branch's frag half
#pragma unroll
    for (int kb = 0; kb < 4; kb++) {
        short8 a = Ar[kb];
#pragma unroll
        for (int n4 = 0; n4 < 16; n4++) {
            short8 b = *(const short8*)(bbase + (size_t)(n4 * 64 + lane) * 16);
            acc[n4] = __builtin_amdgcn_mfma_f32_16x16x32_bf16(a, b, acc[n4], 0, 0, 0);
        }
        __syncthreads();                              // all B reads done
        if (kb < 3) {
            const ushort_t* gsrc = wfrag + ((size_t)(kb + 1) * 2048 + w * 512 + lane) * 8;
            char* ldst = sbuf + (size_t)(w * 512) * 16;
#pragma unroll
            for (int i = 0; i < 8; i++)
                gload_lds16(gsrc + i * 64 * 8, ldst + i * 64 * 16);
            __syncthreads();                          // staging visible (vmcnt drained)
        }
    }

    // map-branch bias (before LN3 stats)
    if (isM) {
#pragma unroll
        for (int n4 = 0; n4 < 16; n4++) {
            float mb = mbf[n4 * 16 + l16];
#pragma unroll
            for (int r = 0; r < 4; r++) acc[n4][r] += mb;
        }
    }

    // LN stats per px (px = quad*4 + r), own branch: butterfly over the 16
    // o-lanes (d<16 stays inside each l16 group).
    floatx4 s = (floatx4)0.f, q = (floatx4)0.f;
#pragma unroll
    for (int n4 = 0; n4 < 16; n4++)
#pragma unroll
        for (int r = 0; r < 4; r++) {
            float a = acc[n4][r];
            s[r] += a; q[r] += a * a;
        }
#pragma unroll
    for (int d = 1; d < 16; d <<= 1) {
#pragma unroll
        for (int r = 0; r < 4; r++) {
            s[r] += __shfl_xor(s[r], d);
            q[r] += __shfl_xor(q[r], d);
        }
    }
    floatx4 mn, rs;
#pragma unroll
    for (int r = 0; r < 4; r++) {
        mn[r] = s[r] * (1.0f / NO);
        rs[r] = rsqrtf(q[r] * (1.0f / NO) - mn[r] * mn[r] + LN_EPS);
    }

    // normalize + affine in place (own branch's LN params)
    const float* lnw = isM ? ln3wf : ln2wf;
    const float* lnb = isM ? ln3bf : ln2bf;
#pragma unroll
    for (int n4 = 0; n4 < 16; n4++) {
        int o = n4 * 16 + l16;
        float ww = lnw[o], bb = lnb[o];
#pragma unroll
        for (int r = 0; r < 4; r++)
            acc[n4][r] = (acc[n4][r] - mn[r]) * rs[r] * ww + bb;
    }

    // pair-exchange HALF the tiles through the dead stage buffer:
    // even writes its n4=8..15 (odd will finish them), odd writes n4=0..7.
    // Layout per pair (16 KB): [even-half 8KB][odd-half 8KB], lane*16B rows.
    float* preg = (float*)(sbuf + pair * 16384);
    if (!isM) {
#pragma unroll
        for (int j = 0; j < 8; j++)
            *(floatx4*)(preg + j * 256 + lane * 4) = acc[8 + j];
    } else {
#pragma unroll
        for (int j = 0; j < 8; j++)
            *(floatx4*)(preg + 2048 + j * 256 + lane * 4) = acc[j];
    }
    __syncthreads();

    // combine + gelu + store: even finishes n4 0..7 (reads odd's half),
    // odd finishes n4 8..15 (reads even's half). Both do 32 gelus, 8 stores.
    int n4base = isM ? 8 : 0;
    const float* rdp = preg + (isM ? 0 : 2048);
    int batch = pw >> 14;
    int plocal = (pw & 16383) + quad * 4;
#pragma unroll
    for (int j = 0; j < 8; j++) {
        int n4 = n4base + j;
        floatx4 other = *(const floatx4*)(rdp + j * 256 + lane * 4);
        float g0 = gelu_f(acc[n4][0] + other[0]);
        float g1 = gelu_f(acc[n4][1] + other[1]);
        float g2 = gelu_f(acc[n4][2] + other[2]);
        float g3 = gelu_f(acc[n4][3] + other[3]);
        int o = n4 * 16 + l16;
        size_t oi = ((size_t)(batch * NO + o) << 14) + plocal;
        if (isf32) {
            *(float4*)((float*)out + oi) = make_float4(g0, g1, g2, g3);
        } else {
            uint_t p0 = (uint_t)f2bf(g0) | ((uint_t)f2bf(g1) << 16);
            uint_t p1 = (uint_t)f2bf(g2) | ((uint_t)f2bf(g3) << 16);
            *(uint2*)((ushort_t*)out + oi) = make_uint2(p0, p1);
        }
    }
}

// ---------------------------------------------------------------------------
extern "C" void kernel_launch(void* const* d_in, const int* in_sizes, int n_in,
                              void* d_out, int out_size, void* d_ws, size_t ws_size,
                              hipStream_t stream) {
    const void* x      = d_in[0];
    const void* w1     = d_in[1];
    const void* b1     = d_in[2];
    const void* w2     = d_in[3];
    const void* b2     = d_in[4];
    const void* ln1w   = d_in[5];
    const void* ln1b   = d_in[6];
    const void* conv_w = d_in[7];
    const void* ln2w   = d_in[8];
    const void* ln2b   = d_in[9];
    const void* map_w  = d_in[10];
    const void* map_b  = d_in[11];
    const void* ln3w   = d_in[12];
    const void* ln3b   = d_in[13];

    char* ws = (char*)d_ws;
    ushort_t* xT    = (ushort_t*)(ws);                  // 16,777,216 B
    ushort_t* y1    = (ushort_t*)(ws + 16777216);       // 16,777,216 B
    ushort_t* wfrag = (ushort_t*)(ws + 33554432);       // 131,072 B
    ushort_t* w1b   = (ushort_t*)(ws + 33685504);       //   8,192 B
    ushort_t* w2b   = (ushort_t*)(ws + 33693696);       //  25,600 B
    float*    b1f   = (float*)(ws + 33719296);
    float*    b2f   = (float*)(ws + 33719424);
    float*    ln1wf = (float*)(ws + 33721024);
    float*    ln1bf = (float*)(ws + 33721536);
    float*    mbf   = (float*)(ws + 33722048);
    float*    ln2wf = (float*)(ws + 33723072);
    float*    ln2bf = (float*)(ws + 33724096);
    float*    ln3wf = (float*)(ws + 33725120);
    float*    ln3bf = (float*)(ws + 33726144);
    int*      flag  = (int*)(ws + 33727168);
    const size_t NEED_SMALL = 33727184;
    ushort_t* wkT   = (ushort_t*)(ws + 33727232);       // 52,428,800 B
    const size_t NEED_BIG = 33727232 + (size_t)NKP * NPIX * 2;   // ~86.2 MB

    if (ws_size < NEED_SMALL) {
        int nwords = out_size / 2;
        ksentinel<<<(nwords + 255) / 256, 256, 0, stream>>>((uint_t*)d_out, nwords);
        return;
    }

    kdetect<<<1, 64, 0, stream>>>((const uint_t*)x, flag);
    kprep<<<128, 256, 0, stream>>>(w1, w2, b1, b2, ln1w, ln1b,
                                   ln2w, ln2b, map_b, ln3w, ln3b, flag,
                                   w1b, w2b, b1f, b2f, ln1wf, ln1bf,
                                   ln2wf, ln2bf, mbf, ln3wf, ln3bf);
    kfrag<<<32, 256, 0, stream>>>(conv_w, map_w, flag, wfrag);
    ktrans<<<dim3(8, 128, 4), 256, 0, stream>>>(x, xT, flag);

    if (ws_size >= NEED_BIG) {
        k1a<<<1024, 256, 0, stream>>>(xT, w1b, b1f, w2b, b2f, wkT);
        k1b<<<1024, 512, 0, stream>>>(xT, wkT, ln1wf, ln1bf, y1);
    } else {
        k1_fused<<<dim3(16, 64, 4), 64, 0, stream>>>(xT, w1b, b1f, w2b, b2f,
                                                     ln1wf, ln1bf, y1);
    }

    k23<<<NPIX / 32, 256, 0, stream>>>(y1, xT, wfrag, mbf,
                                       ln2wf, ln2bf, ln3wf, ln3bf, d_out, flag);
}

// Round 5
// 311.391 us; speedup vs baseline: 1.0657x; 1.0657x over previous
//
#include <hip/hip_runtime.h>

typedef unsigned short ushort_t;
typedef unsigned int uint_t;

#define NB 4
#define NC 128
#define NH 128
#define NW 128
#define NPIX 65536   // NB*NH*NW
#define NMID 32
#define NKK 49
#define NK 392
#define NKP 400      // NK padded to 25 n-tiles of 16
#define NO 256
#define LN_EPS 1e-6f

typedef __attribute__((ext_vector_type(8))) short short8;
typedef __attribute__((ext_vector_type(4))) float floatx4;

__device__ __forceinline__ float bf2f(ushort_t u) {
    union { uint_t i; float f; } v; v.i = ((uint_t)u) << 16; return v.f;
}
__device__ __forceinline__ float bf2f_lo(uint_t u) {
    union { uint_t i; float f; } v; v.i = u << 16; return v.f;
}
__device__ __forceinline__ float bf2f_hi(uint_t u) {
    union { uint_t i; float f; } v; v.i = u & 0xffff0000u; return v.f;
}
__device__ __forceinline__ ushort_t f2bf(float f) {
    union { float f; uint_t i; } v; v.f = f;
    uint_t x = v.i;
    uint_t r = (x + 0x7FFFu + ((x >> 16) & 1u)) >> 16;
    return (ushort_t)r;
}
__device__ __forceinline__ float gelu_f(float x) {
    return 0.5f * x * (1.0f + erff(x * 0.70710678118654752f));
}
__device__ __forceinline__ float ldin(const void* p, int i, int isf32) {
    return isf32 ? ((const float*)p)[i] : bf2f(((const ushort_t*)p)[i]);
}
// global -> LDS direct DMA, 16B per lane; LDS dest = uniform base + lane*16
__device__ __forceinline__ void gload_lds16(const void* g, void* l) {
    __builtin_amdgcn_global_load_lds(
        (const __attribute__((address_space(1))) void*)g,
        (__attribute__((address_space(3))) void*)l, 16, 0, 0);
}

// ---------------------------------------------------------------------------
__global__ void kdetect(const uint_t* __restrict__ xw, int* __restrict__ flag) {
    int lane = threadIdx.x;
    int cnt = 0;
    for (int j = 0; j < 8; j++) {
        uint_t w = xw[lane * 8 + j];
        uint_t e = (w >> 7) & 0xffu;
        if (e >= 110u && e <= 135u) cnt++;
    }
    for (int d = 1; d < 64; d <<= 1) cnt += __shfl_xor(cnt, d);
    if (lane == 0) flag[0] = (cnt < 256) ? 1 : 0;
}

__global__ void ksentinel(uint_t* __restrict__ out, int nwords) {
    int i = blockIdx.x * 256 + threadIdx.x;
    if (i < nwords) out[i] = 0x40004000u;
}

// ---------------------------------------------------------------------------
// K0a: transpose x (B,C,H,W) -> xT (B,H,W,C) canonical bf16.
// ---------------------------------------------------------------------------
__global__ __launch_bounds__(256) void ktrans(const void* __restrict__ x,
                                              ushort_t* __restrict__ xT,
                                              const int* __restrict__ flag) {
    int isf32 = flag[0];
    int b = blockIdx.z, h = blockIdx.y;
    int wchunk = blockIdx.x & 1, cchunk = blockIdx.x >> 1;
    int w0 = wchunk << 6, c0 = cchunk << 5;
    __shared__ ushort_t tile[32][66];
    int tx = threadIdx.x & 63, ty = threadIdx.x >> 6;
    for (int r = 0; r < 32; r += 4) {
        int idx = (((b * NC + c0 + r + ty) * NH) + h) * NW + w0 + tx;
        tile[r + ty][tx] = isf32 ? f2bf(((const float*)x)[idx])
                                 : ((const ushort_t*)x)[idx];
    }
    __syncthreads();
    int cc = threadIdx.x & 31, wq = threadIdx.x >> 5;
    for (int pp = 0; pp < 64; pp += 8) {
        int wx = pp + wq;
        xT[((size_t)((b * NH + h) * NW) + w0 + wx) * NC + c0 + cc] = tile[cc][wx];
    }
}

// ---------------------------------------------------------------------------
// K0b: param prep (w1b/w2b for k1a; small vectors -> fp32).
// ---------------------------------------------------------------------------
__global__ __launch_bounds__(256) void kprep(const void* w1, const void* w2,
                                             const void* b1, const void* b2,
                                             const void* ln1w, const void* ln1b,
                                             const void* ln2w, const void* ln2b,
                                             const void* map_b,
                                             const void* ln3w, const void* ln3b,
                                             const int* __restrict__ flag,
                                             ushort_t* __restrict__ w1b,
                                             ushort_t* __restrict__ w2b,
                                             float* __restrict__ b1f,
                                             float* __restrict__ b2f,
                                             float* __restrict__ ln1wf,
                                             float* __restrict__ ln1bf,
                                             float* __restrict__ ln2wf,
                                             float* __restrict__ ln2bf,
                                             float* __restrict__ mbf,
                                             float* __restrict__ ln3wf,
                                             float* __restrict__ ln3bf) {
    int isf32 = flag[0];
    int i = blockIdx.x * 256 + threadIdx.x;
    if (i < NMID * NC) w1b[i] = f2bf(ldin(w1, i, isf32));
    if (i < NKP * NMID) w2b[i] = (i < NK * NMID) ? f2bf(ldin(w2, i, isf32))
                                                 : (ushort_t)0;
    if (i < NMID) b1f[i] = ldin(b1, i, isf32);
    if (i < NKP)  b2f[i] = (i < NK) ? ldin(b2, i, isf32) : 0.f;
    if (i < NC) { ln1wf[i] = ldin(ln1w, i, isf32); ln1bf[i] = ldin(ln1b, i, isf32); }
    if (i < NO) {
        ln2wf[i] = ldin(ln2w, i, isf32); ln2bf[i] = ldin(ln2b, i, isf32);
        mbf[i]   = ldin(map_b, i, isf32);
        ln3wf[i] = ldin(ln3w, i, isf32); ln3bf[i] = ldin(ln3b, i, isf32);
    }
}

// ---------------------------------------------------------------------------
// KFRAG: repack conv_w/map_w into k-block-major MFMA-fragment order for k23:
// chunk id cid = [kb:2][br:1][n4:4][lane:6], chunk = 8 bf16 = 16 B.
// Each kb-tile (2048 chunks = 32 KB) is CONTIGUOUS -> linear global_load_lds
// target in k23. o = n4*16 + (lane&15), ch = kb*32 + (lane>>4)*8 .. +8.
// grid 32 x 256.
// ---------------------------------------------------------------------------
__global__ __launch_bounds__(256) void kfrag(const void* conv_w, const void* map_w,
                                             const int* __restrict__ flag,
                                             ushort_t* __restrict__ wfrag) {
    int isf32 = flag[0];
    int cid = blockIdx.x * 256 + threadIdx.x;   // [0, 8192)
    int lane = cid & 63, n4 = (cid >> 6) & 15, br = (cid >> 10) & 1, kb = cid >> 11;
    int o = n4 * 16 + (lane & 15);
    int ch0 = kb * 32 + (lane >> 4) * 8;
    const void* src = br ? map_w : conv_w;
    ushort_t* dst = wfrag + (size_t)cid * 8;
#pragma unroll
    for (int j = 0; j < 8; j++)
        dst[j] = f2bf(ldin(src, o * NC + ch0 + j, isf32));
}

// ---------------------------------------------------------------------------
// K1a: wk producer (unchanged). grid 1024, block 256.
// ---------------------------------------------------------------------------
__global__ __launch_bounds__(256) void k1a(const ushort_t* __restrict__ xT,
                                           const ushort_t* __restrict__ w1b,
                                           const float* __restrict__ b1f,
                                           const ushort_t* __restrict__ w2b,
                                           const float* __restrict__ b2f,
                                           ushort_t* __restrict__ wkT) {
    __shared__ ushort_t midbuf[64 * 32];
    __shared__ ushort_t wkstage[NKP * 66];

    int t = threadIdx.x;
    int lane = t & 63;
    int w = __builtin_amdgcn_readfirstlane(t >> 6);
    int l16 = lane & 15, quad = lane >> 4;
    int tileid = blockIdx.x;
    int tilex = tileid & 15, tiley = (tileid >> 4) & 15, b = tileid >> 8;
    int h0 = tiley * 8, w0 = tilex * 8;

    int lpx_a = 16 * w + l16;
    int py = lpx_a >> 3, pxx = lpx_a & 7;
    const ushort_t* abase = xT + (size_t)((b * NH + h0 + py) * NW + w0 + pxx) * NC + quad * 8;
    floatx4 am0 = (floatx4)0.f, am1 = (floatx4)0.f;
#pragma unroll
    for (int kb = 0; kb < 4; kb++) {
        short8 a   = *(const short8*)(abase + kb * 32);
        short8 b0  = *(const short8*)(w1b + (l16) * NC + kb * 32 + quad * 8);
        short8 b1v = *(const short8*)(w1b + (16 + l16) * NC + kb * 32 + quad * 8);
        am0 = __builtin_amdgcn_mfma_f32_16x16x32_bf16(a, b0, am0, 0, 0, 0);
        am1 = __builtin_amdgcn_mfma_f32_16x16x32_bf16(a, b1v, am1, 0, 0, 0);
    }
    {
        float bia0 = b1f[l16], bia1 = b1f[16 + l16];
#pragma unroll
        for (int r = 0; r < 4; r++) {
            int m = 16 * w + quad * 4 + r;
            midbuf[m * 32 + l16]      = f2bf(fmaxf(am0[r] + bia0, 0.f));
            midbuf[m * 32 + 16 + l16] = f2bf(fmaxf(am1[r] + bia1, 0.f));
        }
    }
    __syncthreads();

    short8 aM = *(const short8*)(midbuf + (16 * w + l16) * 32 + quad * 8);
#pragma unroll
    for (int nt = 0; nt < 25; nt++) {
        int n = nt * 16 + l16;
        short8 bw = *(const short8*)(w2b + n * 32 + quad * 8);
        floatx4 c = __builtin_amdgcn_mfma_f32_16x16x32_bf16(aM, bw, (floatx4)0.f, 0, 0, 0);
        float bias = b2f[n];
#pragma unroll
        for (int r = 0; r < 4; r++)
            wkstage[n * 66 + 16 * w + quad * 4 + r] = f2bf(c[r] + bias);
    }
    __syncthreads();

    int krow = t >> 5, px2 = t & 31;
    for (int it = 0; it < 50; it++) {
        int k = it * 8 + krow;
        uint_t v = *(const uint_t*)&wkstage[k * 66 + 2 * px2];
        *(uint_t*)&wkT[(size_t)k * NPIX + tileid * 64 + 2 * px2] = v;
    }
}

// ---------------------------------------------------------------------------
// K1b v3 (unchanged from round 8). grid 1024, block 512.
// ---------------------------------------------------------------------------
__global__ __launch_bounds__(512) void k1b(const ushort_t* __restrict__ xT,
                                           const ushort_t* __restrict__ wkT,
                                           const float* __restrict__ ln1wf,
                                           const float* __restrict__ ln1bf,
                                           ushort_t* __restrict__ y1) {
    __shared__ __align__(16) char smem[50432];
    uint4* x8   = (uint4*)smem;
    float* sred = (float*)smem;

    int t = threadIdx.x;
    int lane = t & 63;
    int w = __builtin_amdgcn_readfirstlane(t >> 6);
    int tileid = blockIdx.x;
    int tilex = tileid & 15, tiley = (tileid >> 4) & 15, b = tileid >> 8;
    int h0 = tiley * 8, w0 = tilex * 8;
    int py = lane >> 3, pxx = lane & 7;

    const ushort_t* wkbase = wkT + (size_t)(w * NKK) * NPIX + tileid * 64 + lane;
    uint_t wkp[25];
#pragma unroll
    for (int j = 0; j < 24; j++) {
        uint_t lo = wkbase[(size_t)(2 * j) * NPIX];
        uint_t hi = wkbase[(size_t)(2 * j + 1) * NPIX];
        wkp[j] = lo | (hi << 16);
    }
    wkp[24] = wkbase[(size_t)48 * NPIX];

    for (int it = 0; it < 7; it++) {
        int idx = it * 512 + t;
        if (idx < 3136) {
            int oct = idx & 15, hp = idx >> 4;
            int hy = hp / 14, hx = hp - hy * 14;
            int gh = h0 + hy - 3, gw = w0 + hx - 3;
            uint4 v = make_uint4(0u, 0u, 0u, 0u);
            if ((unsigned)gh < (unsigned)NH && (unsigned)gw < (unsigned)NW) {
                v = *(const uint4*)&xT[(size_t)((b * NH + gh) * NW + gw) * NC + 8 * oct];
            }
            x8[oct * 197 + hp] = v;
        }
    }
    __syncthreads();

    int base0 = py * 14 + pxx;
    float a[16];
#pragma unroll
    for (int j = 0; j < 16; j++) a[j] = 0.f;

#pragma unroll
    for (int tap = 0; tap < NKK; tap++) {
        float wkf = (tap & 1) ? bf2f((ushort_t)(wkp[tap >> 1] >> 16))
                              : bf2f((ushort_t)(wkp[tap >> 1] & 0xffffu));
        int xa = base0 + (tap / 7) * 14 + (tap % 7);
        uint4 u0 = x8[(2 * w) * 197 + xa];
        uint4 u1 = x8[(2 * w + 1) * 197 + xa];
        a[0]  = fmaf(wkf, bf2f_lo(u0.x), a[0]);
        a[1]  = fmaf(wkf, bf2f_hi(u0.x), a[1]);
        a[2]  = fmaf(wkf, bf2f_lo(u0.y), a[2]);
        a[3]  = fmaf(wkf, bf2f_hi(u0.y), a[3]);
        a[4]  = fmaf(wkf, bf2f_lo(u0.z), a[4]);
        a[5]  = fmaf(wkf, bf2f_hi(u0.z), a[5]);
        a[6]  = fmaf(wkf, bf2f_lo(u0.w), a[6]);
        a[7]  = fmaf(wkf, bf2f_hi(u0.w), a[7]);
        a[8]  = fmaf(wkf, bf2f_lo(u1.x), a[8]);
        a[9]  = fmaf(wkf, bf2f_hi(u1.x), a[9]);
        a[10] = fmaf(wkf, bf2f_lo(u1.y), a[10]);
        a[11] = fmaf(wkf, bf2f_hi(u1.y), a[11]);
        a[12] = fmaf(wkf, bf2f_lo(u1.z), a[12]);
        a[13] = fmaf(wkf, bf2f_hi(u1.z), a[13]);
        a[14] = fmaf(wkf, bf2f_lo(u1.w), a[14]);
        a[15] = fmaf(wkf, bf2f_hi(u1.w), a[15]);
    }
    __syncthreads();

    float s = 0.f, sq = 0.f;
#pragma unroll
    for (int j = 0; j < 16; j++) { s += a[j]; sq += a[j] * a[j]; }
    sred[(w * 64 + lane) * 2]     = s;
    sred[(w * 64 + lane) * 2 + 1] = sq;
    __syncthreads();
    float ts = 0.f, tq = 0.f;
#pragma unroll
    for (int r = 0; r < 8; r++) {
        ts += sred[(r * 64 + lane) * 2];
        tq += sred[(r * 64 + lane) * 2 + 1];
    }
    float mean = ts * (1.0f / NC);
    float var = tq * (1.0f / NC) - mean * mean;
    float rstd = rsqrtf(var + LN_EPS);

    int p = (b * NH + h0 + py) * NW + w0 + pxx;
    uint_t pk[8];
#pragma unroll
    for (int j = 0; j < 8; j++) {
        int c0 = 16 * w + 2 * j;
        float g0 = gelu_f((a[2 * j] - mean) * rstd * ln1wf[c0] + ln1bf[c0]);
        float g1 = gelu_f((a[2 * j + 1] - mean) * rstd * ln1wf[c0 + 1] + ln1bf[c0 + 1]);
        pk[j] = (uint_t)f2bf(g0) | ((uint_t)f2bf(g1) << 16);
    }
    uint4* dst = (uint4*)(y1 + (size_t)p * NC + 16 * w);
    dst[0] = make_uint4(pk[0], pk[1], pk[2], pk[3]);
    dst[1] = make_uint4(pk[4], pk[5], pk[6], pk[7]);
}

// ---------------------------------------------------------------------------
// K1 fused fallback — used only if ws too small for wkT.
// ---------------------------------------------------------------------------
__global__ __launch_bounds__(64) void k1_fused(const ushort_t* __restrict__ xT,
                                               const ushort_t* __restrict__ w1b,
                                               const float* __restrict__ b1f,
                                               const ushort_t* __restrict__ w2b,
                                               const float* __restrict__ b2f,
                                               const float* __restrict__ ln1wf,
                                               const float* __restrict__ ln1bf,
                                               ushort_t* __restrict__ y1) {
    __shared__ ushort_t midbuf[16 * 32];
    __shared__ ushort_t wkbuf[16 * NKP];

    int lane = threadIdx.x;
    int l16 = lane & 15, quad = lane >> 4;
    int b = blockIdx.z;
    int h0 = blockIdx.y * 2, w0 = blockIdx.x * 8;

    int Pa = (b * NH + h0 + (l16 >> 3)) * NW + w0 + (l16 & 7);
    const ushort_t* abase = xT + (size_t)Pa * NC + quad * 8;
    floatx4 am0 = (floatx4)0.f, am1 = (floatx4)0.f;
#pragma unroll
    for (int kb = 0; kb < 4; kb++) {
        short8 a   = *(const short8*)(abase + kb * 32);
        short8 b0  = *(const short8*)(w1b + (l16) * NC + kb * 32 + quad * 8);
        short8 b1v = *(const short8*)(w1b + (16 + l16) * NC + kb * 32 + quad * 8);
        am0 = __builtin_amdgcn_mfma_f32_16x16x32_bf16(a, b0, am0, 0, 0, 0);
        am1 = __builtin_amdgcn_mfma_f32_16x16x32_bf16(a, b1v, am1, 0, 0, 0);
    }
    {
        float bia0 = b1f[l16], bia1 = b1f[16 + l16];
#pragma unroll
        for (int r = 0; r < 4; r++) {
            int m = quad * 4 + r;
            midbuf[m * 32 + l16]      = f2bf(fmaxf(am0[r] + bia0, 0.f));
            midbuf[m * 32 + 16 + l16] = f2bf(fmaxf(am1[r] + bia1, 0.f));
        }
    }
    __syncthreads();

    short8 aM = *(const short8*)(midbuf + l16 * 32 + quad * 8);
#pragma unroll
    for (int nt = 0; nt < 25; nt++) {
        int n = nt * 16 + l16;
        short8 bw = *(const short8*)(w2b + n * 32 + quad * 8);
        floatx4 c = __builtin_amdgcn_mfma_f32_16x16x32_bf16(aM, bw, (floatx4)0.f, 0, 0, 0);
        float bias = b2f[n];
#pragma unroll
        for (int r = 0; r < 4; r++)
            wkbuf[(quad * 4 + r) * NKP + n] = f2bf(c[r] + bias);
    }
    __syncthreads();

    int g = lane >> 3;
    float l1w0 = ln1wf[2 * lane], l1w1 = ln1wf[2 * lane + 1];
    float l1b0 = ln1bf[2 * lane], l1b1 = ln1bf[2 * lane + 1];

    for (int i = 0; i < 16; i++) {
        int hh0 = h0 + (i >> 3), ww0 = w0 + (i & 7);
        int p = (b * NH + hh0) * NW + ww0;
        const ushort_t* wkrow = wkbuf + i * NKP + g * NKK;
        float a0 = 0.f, a1 = 0.f;
#pragma unroll
        for (int dy = -3; dy <= 3; dy++) {
            int hh = hh0 + dy;
            if ((unsigned)hh >= (unsigned)NH) continue;
#pragma unroll
            for (int dx = -3; dx <= 3; dx++) {
                int ww = ww0 + dx;
                if ((unsigned)ww >= (unsigned)NW) continue;
                float wkv = bf2f(wkrow[(dy + 3) * 7 + (dx + 3)]);
                uint_t xp = *(const uint_t*)(xT + ((size_t)(p + dy * NW + dx)) * NC + 2 * lane);
                a0 = fmaf(wkv, bf2f((ushort_t)(xp & 0xffffu)), a0);
                a1 = fmaf(wkv, bf2f((ushort_t)(xp >> 16)), a1);
            }
        }
        float s = a0 + a1, sq = a0 * a0 + a1 * a1;
#pragma unroll
        for (int d = 1; d < 64; d <<= 1) {
            s  += __shfl_xor(s, d);
            sq += __shfl_xor(sq, d);
        }
        float mean = s * (1.0f / NC);
        float var = sq * (1.0f / NC) - mean * mean;
        float rstd = rsqrtf(var + LN_EPS);
        float g0 = gelu_f((a0 - mean) * rstd * l1w0 + l1b0);
        float g1 = gelu_f((a1 - mean) * rstd * l1w1 + l1b1);
        uint_t pk = (uint_t)f2bf(g0) | ((uint_t)f2bf(g1) << 16);
        *(uint_t*)(y1 + (size_t)p * NC + 2 * lane) = pk;
    }
}

// ---------------------------------------------------------------------------
// K23 v8: v7 structure (branch-split wave pairs) with the spill fixed.
// Post-mortem r3: __launch_bounds__(256,4) => 128-reg budget; compiler split
// 64 VGPR + 64 AGPR and spilled the epilogue's 16-floatx4 live set to scratch
// (WRITE_SIZE 65->772 MB = 2048 blocks x ~345 KB spill writeback). Fix:
// min-waves=3 => 168-reg budget; kernel needs ~110-120 => no spill, still
// 12 waves/CU (2x v6's occupancy). 32KB LDS => 3 blocks/CU co-resident.
// Everything else identical to v7 (math op-for-op identical to v6).
// grid 2048, block 256.
// ---------------------------------------------------------------------------
__global__ __launch_bounds__(256, 3) void k23(const ushort_t* __restrict__ y1,
                                              const ushort_t* __restrict__ xT,
                                              const ushort_t* __restrict__ wfrag,
                                              const float* __restrict__ mbf,
                                              const float* __restrict__ ln2wf,
                                              const float* __restrict__ ln2bf,
                                              const float* __restrict__ ln3wf,
                                              const float* __restrict__ ln3bf,
                                              void* __restrict__ out,
                                              const int* __restrict__ flag) {
    __shared__ __align__(16) char sbuf[32768];   // B stage, reused for exchange

    int isf32 = flag[0];
    int t = threadIdx.x;
    int lane = t & 63;
    int w = __builtin_amdgcn_readfirstlane(t >> 6);   // 0..3
    int quad = lane >> 4, l16 = lane & 15;
    int pair = w >> 1;                                // 0..1
    int isM  = w & 1;                                 // 0=conv(y1,LN2) 1=map(xT,LN3)

    int P0 = blockIdx.x * 32;
    int pw = P0 + pair * 16;                          // this pair's first pixel
    const ushort_t* Abase = (isM ? xT : y1) + (size_t)(pw + l16) * NC + quad * 8;

    // stage kb=0 B-tile (32KB): wave w covers chunks [w*512, w*512+512)
    {
        const ushort_t* gsrc = wfrag + (size_t)(w * 512 + lane) * 8;
        char* ldst = sbuf + (size_t)(w * 512) * 16;
#pragma unroll
        for (int i = 0; i < 8; i++)
            gload_lds16(gsrc + i * 64 * 8, ldst + i * 64 * 16);
    }
    // A operands for all 4 k-blocks (own branch only), hoisted to registers
    short8 Ar[4];
#pragma unroll
    for (int kb = 0; kb < 4; kb++) Ar[kb] = *(const short8*)(Abase + kb * 32);

    __syncthreads();

    floatx4 acc[16];
#pragma unroll
    for (int n4 = 0; n4 < 16; n4++) acc[n4] = (floatx4)0.f;

    const char* bbase = sbuf + isM * 16384;           // own branch's frag half
#pragma unroll
    for (int kb = 0; kb < 4; kb++) {
        short8 a = Ar[kb];
#pragma unroll
        for (int n4 = 0; n4 < 16; n4++) {
            short8 b = *(const short8*)(bbase + (size_t)(n4 * 64 + lane) * 16);
            acc[n4] = __builtin_amdgcn_mfma_f32_16x16x32_bf16(a, b, acc[n4], 0, 0, 0);
        }
        __syncthreads();                              // all B reads done
        if (kb < 3) {
            const ushort_t* gsrc = wfrag + ((size_t)(kb + 1) * 2048 + w * 512 + lane) * 8;
            char* ldst = sbuf + (size_t)(w * 512) * 16;
#pragma unroll
            for (int i = 0; i < 8; i++)
                gload_lds16(gsrc + i * 64 * 8, ldst + i * 64 * 16);
            __syncthreads();                          // staging visible (vmcnt drained)
        }
    }

    // map-branch bias (before LN3 stats)
    if (isM) {
#pragma unroll
        for (int n4 = 0; n4 < 16; n4++) {
            float mb = mbf[n4 * 16 + l16];
#pragma unroll
            for (int r = 0; r < 4; r++) acc[n4][r] += mb;
        }
    }

    // LN stats per px (px = quad*4 + r), own branch: butterfly over the 16
    // o-lanes (d<16 stays inside each l16 group).
    floatx4 s = (floatx4)0.f, q = (floatx4)0.f;
#pragma unroll
    for (int n4 = 0; n4 < 16; n4++)
#pragma unroll
        for (int r = 0; r < 4; r++) {
            float a = acc[n4][r];
            s[r] += a; q[r] += a * a;
        }
#pragma unroll
    for (int d = 1; d < 16; d <<= 1) {
#pragma unroll
        for (int r = 0; r < 4; r++) {
            s[r] += __shfl_xor(s[r], d);
            q[r] += __shfl_xor(q[r], d);
        }
    }
    floatx4 mn, rs;
#pragma unroll
    for (int r = 0; r < 4; r++) {
        mn[r] = s[r] * (1.0f / NO);
        rs[r] = rsqrtf(q[r] * (1.0f / NO) - mn[r] * mn[r] + LN_EPS);
    }

    // normalize + affine in place (own branch's LN params)
    const float* lnw = isM ? ln3wf : ln2wf;
    const float* lnb = isM ? ln3bf : ln2bf;
#pragma unroll
    for (int n4 = 0; n4 < 16; n4++) {
        int o = n4 * 16 + l16;
        float ww = lnw[o], bb = lnb[o];
#pragma unroll
        for (int r = 0; r < 4; r++)
            acc[n4][r] = (acc[n4][r] - mn[r]) * rs[r] * ww + bb;
    }

    // pair-exchange HALF the tiles through the dead stage buffer:
    // even writes its n4=8..15 (odd will finish them), odd writes n4=0..7.
    // Layout per pair (16 KB): [even-half 8KB][odd-half 8KB], lane*16B rows.
    float* preg = (float*)(sbuf + pair * 16384);
    if (!isM) {
#pragma unroll
        for (int j = 0; j < 8; j++)
            *(floatx4*)(preg + j * 256 + lane * 4) = acc[8 + j];
    } else {
#pragma unroll
        for (int j = 0; j < 8; j++)
            *(floatx4*)(preg + 2048 + j * 256 + lane * 4) = acc[j];
    }
    __syncthreads();

    // combine + gelu + store: even finishes n4 0..7 (reads odd's half),
    // odd finishes n4 8..15 (reads even's half). Both do 32 gelus, 8 stores.
    int n4base = isM ? 8 : 0;
    const float* rdp = preg + (isM ? 0 : 2048);
    int batch = pw >> 14;
    int plocal = (pw & 16383) + quad * 4;
#pragma unroll
    for (int j = 0; j < 8; j++) {
        int n4 = n4base + j;
        floatx4 other = *(const floatx4*)(rdp + j * 256 + lane * 4);
        float g0 = gelu_f(acc[n4][0] + other[0]);
        float g1 = gelu_f(acc[n4][1] + other[1]);
        float g2 = gelu_f(acc[n4][2] + other[2]);
        float g3 = gelu_f(acc[n4][3] + other[3]);
        int o = n4 * 16 + l16;
        size_t oi = ((size_t)(batch * NO + o) << 14) + plocal;
        if (isf32) {
            *(float4*)((float*)out + oi) = make_float4(g0, g1, g2, g3);
        } else {
            uint_t p0 = (uint_t)f2bf(g0) | ((uint_t)f2bf(g1) << 16);
            uint_t p1 = (uint_t)f2bf(g2) | ((uint_t)f2bf(g3) << 16);
            *(uint2*)((ushort_t*)out + oi) = make_uint2(p0, p1);
        }
    }
}

// ---------------------------------------------------------------------------
extern "C" void kernel_launch(void* const* d_in, const int* in_sizes, int n_in,
                              void* d_out, int out_size, void* d_ws, size_t ws_size,
                              hipStream_t stream) {
    const void* x      = d_in[0];
    const void* w1     = d_in[1];
    const void* b1     = d_in[2];
    const void* w2     = d_in[3];
    const void* b2     = d_in[4];
    const void* ln1w   = d_in[5];
    const void* ln1b   = d_in[6];
    const void* conv_w = d_in[7];
    const void* ln2w   = d_in[8];
    const void* ln2b   = d_in[9];
    const void* map_w  = d_in[10];
    const void* map_b  = d_in[11];
    const void* ln3w   = d_in[12];
    const void* ln3b   = d_in[13];

    char* ws = (char*)d_ws;
    ushort_t* xT    = (ushort_t*)(ws);                  // 16,777,216 B
    ushort_t* y1    = (ushort_t*)(ws + 16777216);       // 16,777,216 B
    ushort_t* wfrag = (ushort_t*)(ws + 33554432);       // 131,072 B
    ushort_t* w1b   = (ushort_t*)(ws + 33685504);       //   8,192 B
    ushort_t* w2b   = (ushort_t*)(ws + 33693696);       //  25,600 B
    float*    b1f   = (float*)(ws + 33719296);
    float*    b2f   = (float*)(ws + 33719424);
    float*    ln1wf = (float*)(ws + 33721024);
    float*    ln1bf = (float*)(ws + 33721536);
    float*    mbf   = (float*)(ws + 33722048);
    float*    ln2wf = (float*)(ws + 33723072);
    float*    ln2bf = (float*)(ws + 33724096);
    float*    ln3wf = (float*)(ws + 33725120);
    float*    ln3bf = (float*)(ws + 33726144);
    int*      flag  = (int*)(ws + 33727168);
    const size_t NEED_SMALL = 33727184;
    ushort_t* wkT   = (ushort_t*)(ws + 33727232);       // 52,428,800 B
    const size_t NEED_BIG = 33727232 + (size_t)NKP * NPIX * 2;   // ~86.2 MB

    if (ws_size < NEED_SMALL) {
        int nwords = out_size / 2;
        ksentinel<<<(nwords + 255) / 256, 256, 0, stream>>>((uint_t*)d_out, nwords);
        return;
    }

    kdetect<<<1, 64, 0, stream>>>((const uint_t*)x, flag);
    kprep<<<128, 256, 0, stream>>>(w1, w2, b1, b2, ln1w, ln1b,
                                   ln2w, ln2b, map_b, ln3w, ln3b, flag,
                                   w1b, w2b, b1f, b2f, ln1wf, ln1bf,
                                   ln2wf, ln2bf, mbf, ln3wf, ln3bf);
    kfrag<<<32, 256, 0, stream>>>(conv_w, map_w, flag, wfrag);
    ktrans<<<dim3(8, 128, 4), 256, 0, stream>>>(x, xT, flag);

    if (ws_size >= NEED_BIG) {
        k1a<<<1024, 256, 0, stream>>>(xT, w1b, b1f, w2b, b2f, wkT);
        k1b<<<1024, 512, 0, stream>>>(xT, wkT, ln1wf, ln1bf, y1);
    } else {
        k1_fused<<<dim3(16, 64, 4), 64, 0, stream>>>(xT, w1b, b1f, w2b, b2f,
                                                     ln1wf, ln1bf, y1);
    }

    k23<<<NPIX / 32, 256, 0, stream>>>(y1, xT, wfrag, mbf,
                                       ln2wf, ln2bf, ln3wf, ln3bf, d_out, flag);
}

// Round 6
// 228.509 us; speedup vs baseline: 1.4522x; 1.3627x over previous
//
#include <hip/hip_runtime.h>

typedef unsigned short ushort_t;
typedef unsigned int uint_t;

#define NB 4
#define NC 128
#define NH 128
#define NW 128
#define NPIX 65536   // NB*NH*NW
#define NMID 32
#define NKK 49
#define NK 392
#define NKP 400      // NK padded to 25 n-tiles of 16
#define NO 256
#define LN_EPS 1e-6f

typedef __attribute__((ext_vector_type(8))) short short8;
typedef __attribute__((ext_vector_type(4))) float floatx4;

__device__ __forceinline__ float bf2f(ushort_t u) {
    union { uint_t i; float f; } v; v.i = ((uint_t)u) << 16; return v.f;
}
__device__ __forceinline__ float bf2f_lo(uint_t u) {
    union { uint_t i; float f; } v; v.i = u << 16; return v.f;
}
__device__ __forceinline__ float bf2f_hi(uint_t u) {
    union { uint_t i; float f; } v; v.i = u & 0xffff0000u; return v.f;
}
__device__ __forceinline__ ushort_t f2bf(float f) {
    union { float f; uint_t i; } v; v.f = f;
    uint_t x = v.i;
    uint_t r = (x + 0x7FFFu + ((x >> 16) & 1u)) >> 16;
    return (ushort_t)r;
}
__device__ __forceinline__ float gelu_f(float x) {
    return 0.5f * x * (1.0f + erff(x * 0.70710678118654752f));
}
__device__ __forceinline__ float ldin(const void* p, int i, int isf32) {
    return isf32 ? ((const float*)p)[i] : bf2f(((const ushort_t*)p)[i]);
}
// global -> LDS direct DMA, 16B per lane; LDS dest = uniform base + lane*16
__device__ __forceinline__ void gload_lds16(const void* g, void* l) {
    __builtin_amdgcn_global_load_lds(
        (const __attribute__((address_space(1))) void*)g,
        (__attribute__((address_space(3))) void*)l, 16, 0, 0);
}

// ---------------------------------------------------------------------------
__global__ void kdetect(const uint_t* __restrict__ xw, int* __restrict__ flag) {
    int lane = threadIdx.x;
    int cnt = 0;
    for (int j = 0; j < 8; j++) {
        uint_t w = xw[lane * 8 + j];
        uint_t e = (w >> 7) & 0xffu;
        if (e >= 110u && e <= 135u) cnt++;
    }
    for (int d = 1; d < 64; d <<= 1) cnt += __shfl_xor(cnt, d);
    if (lane == 0) flag[0] = (cnt < 256) ? 1 : 0;
}

__global__ void ksentinel(uint_t* __restrict__ out, int nwords) {
    int i = blockIdx.x * 256 + threadIdx.x;
    if (i < nwords) out[i] = 0x40004000u;
}

// ---------------------------------------------------------------------------
// K0a: transpose x (B,C,H,W) -> xT (B,H,W,C) canonical bf16.
// ---------------------------------------------------------------------------
__global__ __launch_bounds__(256) void ktrans(const void* __restrict__ x,
                                              ushort_t* __restrict__ xT,
                                              const int* __restrict__ flag) {
    int isf32 = flag[0];
    int b = blockIdx.z, h = blockIdx.y;
    int wchunk = blockIdx.x & 1, cchunk = blockIdx.x >> 1;
    int w0 = wchunk << 6, c0 = cchunk << 5;
    __shared__ ushort_t tile[32][66];
    int tx = threadIdx.x & 63, ty = threadIdx.x >> 6;
    for (int r = 0; r < 32; r += 4) {
        int idx = (((b * NC + c0 + r + ty) * NH) + h) * NW + w0 + tx;
        tile[r + ty][tx] = isf32 ? f2bf(((const float*)x)[idx])
                                 : ((const ushort_t*)x)[idx];
    }
    __syncthreads();
    int cc = threadIdx.x & 31, wq = threadIdx.x >> 5;
    for (int pp = 0; pp < 64; pp += 8) {
        int wx = pp + wq;
        xT[((size_t)((b * NH + h) * NW) + w0 + wx) * NC + c0 + cc] = tile[cc][wx];
    }
}

// ---------------------------------------------------------------------------
// K0b: param prep (w1b/w2b for k1a; small vectors -> fp32).
// ---------------------------------------------------------------------------
__global__ __launch_bounds__(256) void kprep(const void* w1, const void* w2,
                                             const void* b1, const void* b2,
                                             const void* ln1w, const void* ln1b,
                                             const void* ln2w, const void* ln2b,
                                             const void* map_b,
                                             const void* ln3w, const void* ln3b,
                                             const int* __restrict__ flag,
                                             ushort_t* __restrict__ w1b,
                                             ushort_t* __restrict__ w2b,
                                             float* __restrict__ b1f,
                                             float* __restrict__ b2f,
                                             float* __restrict__ ln1wf,
                                             float* __restrict__ ln1bf,
                                             float* __restrict__ ln2wf,
                                             float* __restrict__ ln2bf,
                                             float* __restrict__ mbf,
                                             float* __restrict__ ln3wf,
                                             float* __restrict__ ln3bf) {
    int isf32 = flag[0];
    int i = blockIdx.x * 256 + threadIdx.x;
    if (i < NMID * NC) w1b[i] = f2bf(ldin(w1, i, isf32));
    if (i < NKP * NMID) w2b[i] = (i < NK * NMID) ? f2bf(ldin(w2, i, isf32))
                                                 : (ushort_t)0;
    if (i < NMID) b1f[i] = ldin(b1, i, isf32);
    if (i < NKP)  b2f[i] = (i < NK) ? ldin(b2, i, isf32) : 0.f;
    if (i < NC) { ln1wf[i] = ldin(ln1w, i, isf32); ln1bf[i] = ldin(ln1b, i, isf32); }
    if (i < NO) {
        ln2wf[i] = ldin(ln2w, i, isf32); ln2bf[i] = ldin(ln2b, i, isf32);
        mbf[i]   = ldin(map_b, i, isf32);
        ln3wf[i] = ldin(ln3w, i, isf32); ln3bf[i] = ldin(ln3b, i, isf32);
    }
}

// ---------------------------------------------------------------------------
// KFRAG: repack conv_w/map_w into k-block-major MFMA-fragment order for k23:
// chunk id cid = [kb:2][br:1][n4:4][lane:6], chunk = 8 bf16 = 16 B.
// Each kb-tile (2048 chunks = 32 KB) is CONTIGUOUS -> linear global_load_lds
// target in k23. o = n4*16 + (lane&15), ch = kb*32 + (lane>>4)*8 .. +8.
// grid 32 x 256.
// ---------------------------------------------------------------------------
__global__ __launch_bounds__(256) void kfrag(const void* conv_w, const void* map_w,
                                             const int* __restrict__ flag,
                                             ushort_t* __restrict__ wfrag) {
    int isf32 = flag[0];
    int cid = blockIdx.x * 256 + threadIdx.x;   // [0, 8192)
    int lane = cid & 63, n4 = (cid >> 6) & 15, br = (cid >> 10) & 1, kb = cid >> 11;
    int o = n4 * 16 + (lane & 15);
    int ch0 = kb * 32 + (lane >> 4) * 8;
    const void* src = br ? map_w : conv_w;
    ushort_t* dst = wfrag + (size_t)cid * 8;
#pragma unroll
    for (int j = 0; j < 8; j++)
        dst[j] = f2bf(ldin(src, o * NC + ch0 + j, isf32));
}

// ---------------------------------------------------------------------------
// K1a: wk producer (unchanged). grid 1024, block 256.
// ---------------------------------------------------------------------------
__global__ __launch_bounds__(256) void k1a(const ushort_t* __restrict__ xT,
                                           const ushort_t* __restrict__ w1b,
                                           const float* __restrict__ b1f,
                                           const ushort_t* __restrict__ w2b,
                                           const float* __restrict__ b2f,
                                           ushort_t* __restrict__ wkT) {
    __shared__ ushort_t midbuf[64 * 32];
    __shared__ ushort_t wkstage[NKP * 66];

    int t = threadIdx.x;
    int lane = t & 63;
    int w = __builtin_amdgcn_readfirstlane(t >> 6);
    int l16 = lane & 15, quad = lane >> 4;
    int tileid = blockIdx.x;
    int tilex = tileid & 15, tiley = (tileid >> 4) & 15, b = tileid >> 8;
    int h0 = tiley * 8, w0 = tilex * 8;

    int lpx_a = 16 * w + l16;
    int py = lpx_a >> 3, pxx = lpx_a & 7;
    const ushort_t* abase = xT + (size_t)((b * NH + h0 + py) * NW + w0 + pxx) * NC + quad * 8;
    floatx4 am0 = (floatx4)0.f, am1 = (floatx4)0.f;
#pragma unroll
    for (int kb = 0; kb < 4; kb++) {
        short8 a   = *(const short8*)(abase + kb * 32);
        short8 b0  = *(const short8*)(w1b + (l16) * NC + kb * 32 + quad * 8);
        short8 b1v = *(const short8*)(w1b + (16 + l16) * NC + kb * 32 + quad * 8);
        am0 = __builtin_amdgcn_mfma_f32_16x16x32_bf16(a, b0, am0, 0, 0, 0);
        am1 = __builtin_amdgcn_mfma_f32_16x16x32_bf16(a, b1v, am1, 0, 0, 0);
    }
    {
        float bia0 = b1f[l16], bia1 = b1f[16 + l16];
#pragma unroll
        for (int r = 0; r < 4; r++) {
            int m = 16 * w + quad * 4 + r;
            midbuf[m * 32 + l16]      = f2bf(fmaxf(am0[r] + bia0, 0.f));
            midbuf[m * 32 + 16 + l16] = f2bf(fmaxf(am1[r] + bia1, 0.f));
        }
    }
    __syncthreads();

    short8 aM = *(const short8*)(midbuf + (16 * w + l16) * 32 + quad * 8);
#pragma unroll
    for (int nt = 0; nt < 25; nt++) {
        int n = nt * 16 + l16;
        short8 bw = *(const short8*)(w2b + n * 32 + quad * 8);
        floatx4 c = __builtin_amdgcn_mfma_f32_16x16x32_bf16(aM, bw, (floatx4)0.f, 0, 0, 0);
        float bias = b2f[n];
#pragma unroll
        for (int r = 0; r < 4; r++)
            wkstage[n * 66 + 16 * w + quad * 4 + r] = f2bf(c[r] + bias);
    }
    __syncthreads();

    int krow = t >> 5, px2 = t & 31;
    for (int it = 0; it < 50; it++) {
        int k = it * 8 + krow;
        uint_t v = *(const uint_t*)&wkstage[k * 66 + 2 * px2];
        *(uint_t*)&wkT[(size_t)k * NPIX + tileid * 64 + 2 * px2] = v;
    }
}

// ---------------------------------------------------------------------------
// K1b v3 (unchanged from round 8). grid 1024, block 512.
// ---------------------------------------------------------------------------
__global__ __launch_bounds__(512) void k1b(const ushort_t* __restrict__ xT,
                                           const ushort_t* __restrict__ wkT,
                                           const float* __restrict__ ln1wf,
                                           const float* __restrict__ ln1bf,
                                           ushort_t* __restrict__ y1) {
    __shared__ __align__(16) char smem[50432];
    uint4* x8   = (uint4*)smem;
    float* sred = (float*)smem;

    int t = threadIdx.x;
    int lane = t & 63;
    int w = __builtin_amdgcn_readfirstlane(t >> 6);
    int tileid = blockIdx.x;
    int tilex = tileid & 15, tiley = (tileid >> 4) & 15, b = tileid >> 8;
    int h0 = tiley * 8, w0 = tilex * 8;
    int py = lane >> 3, pxx = lane & 7;

    const ushort_t* wkbase = wkT + (size_t)(w * NKK) * NPIX + tileid * 64 + lane;
    uint_t wkp[25];
#pragma unroll
    for (int j = 0; j < 24; j++) {
        uint_t lo = wkbase[(size_t)(2 * j) * NPIX];
        uint_t hi = wkbase[(size_t)(2 * j + 1) * NPIX];
        wkp[j] = lo | (hi << 16);
    }
    wkp[24] = wkbase[(size_t)48 * NPIX];

    for (int it = 0; it < 7; it++) {
        int idx = it * 512 + t;
        if (idx < 3136) {
            int oct = idx & 15, hp = idx >> 4;
            int hy = hp / 14, hx = hp - hy * 14;
            int gh = h0 + hy - 3, gw = w0 + hx - 3;
            uint4 v = make_uint4(0u, 0u, 0u, 0u);
            if ((unsigned)gh < (unsigned)NH && (unsigned)gw < (unsigned)NW) {
                v = *(const uint4*)&xT[(size_t)((b * NH + gh) * NW + gw) * NC + 8 * oct];
            }
            x8[oct * 197 + hp] = v;
        }
    }
    __syncthreads();

    int base0 = py * 14 + pxx;
    float a[16];
#pragma unroll
    for (int j = 0; j < 16; j++) a[j] = 0.f;

#pragma unroll
    for (int tap = 0; tap < NKK; tap++) {
        float wkf = (tap & 1) ? bf2f((ushort_t)(wkp[tap >> 1] >> 16))
                              : bf2f((ushort_t)(wkp[tap >> 1] & 0xffffu));
        int xa = base0 + (tap / 7) * 14 + (tap % 7);
        uint4 u0 = x8[(2 * w) * 197 + xa];
        uint4 u1 = x8[(2 * w + 1) * 197 + xa];
        a[0]  = fmaf(wkf, bf2f_lo(u0.x), a[0]);
        a[1]  = fmaf(wkf, bf2f_hi(u0.x), a[1]);
        a[2]  = fmaf(wkf, bf2f_lo(u0.y), a[2]);
        a[3]  = fmaf(wkf, bf2f_hi(u0.y), a[3]);
        a[4]  = fmaf(wkf, bf2f_lo(u0.z), a[4]);
        a[5]  = fmaf(wkf, bf2f_hi(u0.z), a[5]);
        a[6]  = fmaf(wkf, bf2f_lo(u0.w), a[6]);
        a[7]  = fmaf(wkf, bf2f_hi(u0.w), a[7]);
        a[8]  = fmaf(wkf, bf2f_lo(u1.x), a[8]);
        a[9]  = fmaf(wkf, bf2f_hi(u1.x), a[9]);
        a[10] = fmaf(wkf, bf2f_lo(u1.y), a[10]);
        a[11] = fmaf(wkf, bf2f_hi(u1.y), a[11]);
        a[12] = fmaf(wkf, bf2f_lo(u1.z), a[12]);
        a[13] = fmaf(wkf, bf2f_hi(u1.z), a[13]);
        a[14] = fmaf(wkf, bf2f_lo(u1.w), a[14]);
        a[15] = fmaf(wkf, bf2f_hi(u1.w), a[15]);
    }
    __syncthreads();

    float s = 0.f, sq = 0.f;
#pragma unroll
    for (int j = 0; j < 16; j++) { s += a[j]; sq += a[j] * a[j]; }
    sred[(w * 64 + lane) * 2]     = s;
    sred[(w * 64 + lane) * 2 + 1] = sq;
    __syncthreads();
    float ts = 0.f, tq = 0.f;
#pragma unroll
    for (int r = 0; r < 8; r++) {
        ts += sred[(r * 64 + lane) * 2];
        tq += sred[(r * 64 + lane) * 2 + 1];
    }
    float mean = ts * (1.0f / NC);
    float var = tq * (1.0f / NC) - mean * mean;
    float rstd = rsqrtf(var + LN_EPS);

    int p = (b * NH + h0 + py) * NW + w0 + pxx;
    uint_t pk[8];
#pragma unroll
    for (int j = 0; j < 8; j++) {
        int c0 = 16 * w + 2 * j;
        float g0 = gelu_f((a[2 * j] - mean) * rstd * ln1wf[c0] + ln1bf[c0]);
        float g1 = gelu_f((a[2 * j + 1] - mean) * rstd * ln1wf[c0 + 1] + ln1bf[c0 + 1]);
        pk[j] = (uint_t)f2bf(g0) | ((uint_t)f2bf(g1) << 16);
    }
    uint4* dst = (uint4*)(y1 + (size_t)p * NC + 16 * w);
    dst[0] = make_uint4(pk[0], pk[1], pk[2], pk[3]);
    dst[1] = make_uint4(pk[4], pk[5], pk[6], pk[7]);
}

// ---------------------------------------------------------------------------
// K1 fused fallback — used only if ws too small for wkT.
// ---------------------------------------------------------------------------
__global__ __launch_bounds__(64) void k1_fused(const ushort_t* __restrict__ xT,
                                               const ushort_t* __restrict__ w1b,
                                               const float* __restrict__ b1f,
                                               const ushort_t* __restrict__ w2b,
                                               const float* __restrict__ b2f,
                                               const float* __restrict__ ln1wf,
                                               const float* __restrict__ ln1bf,
                                               ushort_t* __restrict__ y1) {
    __shared__ ushort_t midbuf[16 * 32];
    __shared__ ushort_t wkbuf[16 * NKP];

    int lane = threadIdx.x;
    int l16 = lane & 15, quad = lane >> 4;
    int b = blockIdx.z;
    int h0 = blockIdx.y * 2, w0 = blockIdx.x * 8;

    int Pa = (b * NH + h0 + (l16 >> 3)) * NW + w0 + (l16 & 7);
    const ushort_t* abase = xT + (size_t)Pa * NC + quad * 8;
    floatx4 am0 = (floatx4)0.f, am1 = (floatx4)0.f;
#pragma unroll
    for (int kb = 0; kb < 4; kb++) {
        short8 a   = *(const short8*)(abase + kb * 32);
        short8 b0  = *(const short8*)(w1b + (l16) * NC + kb * 32 + quad * 8);
        short8 b1v = *(const short8*)(w1b + (16 + l16) * NC + kb * 32 + quad * 8);
        am0 = __builtin_amdgcn_mfma_f32_16x16x32_bf16(a, b0, am0, 0, 0, 0);
        am1 = __builtin_amdgcn_mfma_f32_16x16x32_bf16(a, b1v, am1, 0, 0, 0);
    }
    {
        float bia0 = b1f[l16], bia1 = b1f[16 + l16];
#pragma unroll
        for (int r = 0; r < 4; r++) {
            int m = quad * 4 + r;
            midbuf[m * 32 + l16]      = f2bf(fmaxf(am0[r] + bia0, 0.f));
            midbuf[m * 32 + 16 + l16] = f2bf(fmaxf(am1[r] + bia1, 0.f));
        }
    }
    __syncthreads();

    short8 aM = *(const short8*)(midbuf + l16 * 32 + quad * 8);
#pragma unroll
    for (int nt = 0; nt < 25; nt++) {
        int n = nt * 16 + l16;
        short8 bw = *(const short8*)(w2b + n * 32 + quad * 8);
        floatx4 c = __builtin_amdgcn_mfma_f32_16x16x32_bf16(aM, bw, (floatx4)0.f, 0, 0, 0);
        float bias = b2f[n];
#pragma unroll
        for (int r = 0; r < 4; r++)
            wkbuf[(quad * 4 + r) * NKP + n] = f2bf(c[r] + bias);
    }
    __syncthreads();

    int g = lane >> 3;
    float l1w0 = ln1wf[2 * lane], l1w1 = ln1wf[2 * lane + 1];
    float l1b0 = ln1bf[2 * lane], l1b1 = ln1bf[2 * lane + 1];

    for (int i = 0; i < 16; i++) {
        int hh0 = h0 + (i >> 3), ww0 = w0 + (i & 7);
        int p = (b * NH + hh0) * NW + ww0;
        const ushort_t* wkrow = wkbuf + i * NKP + g * NKK;
        float a0 = 0.f, a1 = 0.f;
#pragma unroll
        for (int dy = -3; dy <= 3; dy++) {
            int hh = hh0 + dy;
            if ((unsigned)hh >= (unsigned)NH) continue;
#pragma unroll
            for (int dx = -3; dx <= 3; dx++) {
                int ww = ww0 + dx;
                if ((unsigned)ww >= (unsigned)NW) continue;
                float wkv = bf2f(wkrow[(dy + 3) * 7 + (dx + 3)]);
                uint_t xp = *(const uint_t*)(xT + ((size_t)(p + dy * NW + dx)) * NC + 2 * lane);
                a0 = fmaf(wkv, bf2f((ushort_t)(xp & 0xffffu)), a0);
                a1 = fmaf(wkv, bf2f((ushort_t)(xp >> 16)), a1);
            }
        }
        float s = a0 + a1, sq = a0 * a0 + a1 * a1;
#pragma unroll
        for (int d = 1; d < 64; d <<= 1) {
            s  += __shfl_xor(s, d);
            sq += __shfl_xor(sq, d);
        }
        float mean = s * (1.0f / NC);
        float var = sq * (1.0f / NC) - mean * mean;
        float rstd = rsqrtf(var + LN_EPS);
        float g0 = gelu_f((a0 - mean) * rstd * l1w0 + l1b0);
        float g1 = gelu_f((a1 - mean) * rstd * l1w1 + l1b1);
        uint_t pk = (uint_t)f2bf(g0) | ((uint_t)f2bf(g1) << 16);
        *(uint_t*)(y1 + (size_t)p * NC + 2 * lane) = pk;
    }
}

// ---------------------------------------------------------------------------
// K23 v9: o-half split wave pairs. Wave (pair, oh) computes BOTH branches for
// 16 px x 128 o (o in [oh*128, +128)): acc = 2x8 floatx4 = 64 regs (AGPR).
// vs v8 (branch split): gelu's v1+v2 are now wave-local -> NO 16KB normalized
// tile exchange; only LN PARTIAL STATS (1 KB) cross the pair via the dead
// stage buffer. Epilogue is per-n4 streamable (small VGPR live set) -> fits
// the (256,3) 168-reg budget without the spill that killed v7/v8
// (WRITE_SIZE 700 MB of scratch). Staging/MFMA counts identical to v8.
// grid 2048, block 256.
// ---------------------------------------------------------------------------
__global__ __launch_bounds__(256, 3) void k23(const ushort_t* __restrict__ y1,
                                              const ushort_t* __restrict__ xT,
                                              const ushort_t* __restrict__ wfrag,
                                              const float* __restrict__ mbf,
                                              const float* __restrict__ ln2wf,
                                              const float* __restrict__ ln2bf,
                                              const float* __restrict__ ln3wf,
                                              const float* __restrict__ ln3bf,
                                              void* __restrict__ out,
                                              const int* __restrict__ flag) {
    __shared__ __align__(16) char sbuf[32768];   // B stage, reused for stats

    int isf32 = flag[0];
    int t = threadIdx.x;
    int lane = t & 63;
    int w = __builtin_amdgcn_readfirstlane(t >> 6);   // 0..3
    int quad = lane >> 4, l16 = lane & 15;
    int pair = w >> 1;                                // 0..1 -> px group
    int oh   = w & 1;                                 // 0..1 -> o-half (128 o's)

    int P0 = blockIdx.x * 32;
    int pw = P0 + pair * 16;                          // this wave's first pixel
    const ushort_t* aYp = y1 + (size_t)(pw + l16) * NC + quad * 8;
    const ushort_t* aXp = xT + (size_t)(pw + l16) * NC + quad * 8;

    // stage kb=0 B-tile (32KB): wave w covers chunks [w*512, w*512+512)
    {
        const ushort_t* gsrc = wfrag + (size_t)(w * 512 + lane) * 8;
        char* ldst = sbuf + (size_t)(w * 512) * 16;
#pragma unroll
        for (int i = 0; i < 8; i++)
            gload_lds16(gsrc + i * 64 * 8, ldst + i * 64 * 16);
    }
    // A operands (both branches) for all 4 k-blocks, hoisted to registers
    short8 Ay[4], Ax[4];
#pragma unroll
    for (int kb = 0; kb < 4; kb++) {
        Ay[kb] = *(const short8*)(aYp + kb * 32);
        Ax[kb] = *(const short8*)(aXp + kb * 32);
    }
    __syncthreads();

    floatx4 accC[8], accM[8];
#pragma unroll
    for (int j = 0; j < 8; j++) { accC[j] = (floatx4)0.f; accM[j] = (floatx4)0.f; }

#pragma unroll
    for (int kb = 0; kb < 4; kb++) {
        short8 ay = Ay[kb], ax = Ax[kb];
#pragma unroll
        for (int j = 0; j < 8; j++) {
            int n4 = oh * 8 + j;
            // tile layout: [br:1][n4:4][lane:6] chunks of 16 B
            short8 bc = *(const short8*)(sbuf + (size_t)(n4 * 64 + lane) * 16);
            short8 bm = *(const short8*)(sbuf + 16384 + (size_t)(n4 * 64 + lane) * 16);
            accC[j] = __builtin_amdgcn_mfma_f32_16x16x32_bf16(ay, bc, accC[j], 0, 0, 0);
            accM[j] = __builtin_amdgcn_mfma_f32_16x16x32_bf16(ax, bm, accM[j], 0, 0, 0);
        }
        __syncthreads();                              // all B reads done
        if (kb < 3) {
            const ushort_t* gsrc = wfrag + ((size_t)(kb + 1) * 2048 + w * 512 + lane) * 8;
            char* ldst = sbuf + (size_t)(w * 512) * 16;
#pragma unroll
            for (int i = 0; i < 8; i++)
                gload_lds16(gsrc + i * 64 * 8, ldst + i * 64 * 16);
            __syncthreads();                          // staging visible (vmcnt drained)
        }
    }

    // map-branch bias (before LN3 stats)
#pragma unroll
    for (int j = 0; j < 8; j++) {
        float mb = mbf[(oh * 8 + j) * 16 + l16];
#pragma unroll
        for (int r = 0; r < 4; r++) accM[j][r] += mb;
    }

    // LN partial stats per px (px = quad*4 + r) over this wave's 128 o's:
    // accumulate over 8 n4, butterfly over the 16 o-lanes (d<16 stays inside
    // each l16 group).
    floatx4 s1 = (floatx4)0.f, q1 = (floatx4)0.f, s2 = (floatx4)0.f, q2 = (floatx4)0.f;
#pragma unroll
    for (int j = 0; j < 8; j++)
#pragma unroll
        for (int r = 0; r < 4; r++) {
            float a = accC[j][r], m = accM[j][r];
            s1[r] += a; q1[r] += a * a;
            s2[r] += m; q2[r] += m * m;
        }
#pragma unroll
    for (int d = 1; d < 16; d <<= 1) {
#pragma unroll
        for (int r = 0; r < 4; r++) {
            s1[r] += __shfl_xor(s1[r], d);
            q1[r] += __shfl_xor(q1[r], d);
            s2[r] += __shfl_xor(s2[r], d);
            q2[r] += __shfl_xor(q2[r], d);
        }
    }

    // exchange partial stats with the pair's other o-half through sbuf (dead):
    // layout [pair:1][oh:1][px:4bits][4 stats] floats = 256 floats = 1 KB.
    float* sstat = (float*)sbuf;
    if (l16 == 0) {
#pragma unroll
        for (int r = 0; r < 4; r++) {
            float* sp = sstat + (((pair * 2 + oh) * 16) + quad * 4 + r) * 4;
            sp[0] = s1[r]; sp[1] = q1[r]; sp[2] = s2[r]; sp[3] = q2[r];
        }
    }
    __syncthreads();

    floatx4 mn1, rs1, mn2, rs2;
#pragma unroll
    for (int r = 0; r < 4; r++) {
        const float* op = sstat + (((pair * 2 + (oh ^ 1)) * 16) + quad * 4 + r) * 4;
        float S1 = s1[r] + op[0], Q1 = q1[r] + op[1];
        float S2 = s2[r] + op[2], Q2 = q2[r] + op[3];
        mn1[r] = S1 * (1.0f / NO);
        rs1[r] = rsqrtf(Q1 * (1.0f / NO) - mn1[r] * mn1[r] + LN_EPS);
        mn2[r] = S2 * (1.0f / NO);
        rs2[r] = rsqrtf(Q2 * (1.0f / NO) - mn2[r] * mn2[r] + LN_EPS);
    }

    // streaming epilogue: per n4, normalize both branches, gelu, direct store
    // (lane's 4 acc components are 4 CONTIGUOUS pixels -> float4/uint2).
    int batch = pw >> 14;
    int plocal = (pw & 16383) + quad * 4;
#pragma unroll
    for (int j = 0; j < 8; j++) {
        int o = (oh * 8 + j) * 16 + l16;
        float l2w = ln2wf[o], l2b = ln2bf[o];
        float l3w = ln3wf[o], l3b = ln3bf[o];
        float4 gv;
        {
            float v1, v2;
            v1 = (accC[j][0] - mn1[0]) * rs1[0] * l2w + l2b;
            v2 = (accM[j][0] - mn2[0]) * rs2[0] * l3w + l3b;
            gv.x = gelu_f(v1 + v2);
            v1 = (accC[j][1] - mn1[1]) * rs1[1] * l2w + l2b;
            v2 = (accM[j][1] - mn2[1]) * rs2[1] * l3w + l3b;
            gv.y = gelu_f(v1 + v2);
            v1 = (accC[j][2] - mn1[2]) * rs1[2] * l2w + l2b;
            v2 = (accM[j][2] - mn2[2]) * rs2[2] * l3w + l3b;
            gv.z = gelu_f(v1 + v2);
            v1 = (accC[j][3] - mn1[3]) * rs1[3] * l2w + l2b;
            v2 = (accM[j][3] - mn2[3]) * rs2[3] * l3w + l3b;
            gv.w = gelu_f(v1 + v2);
        }
        size_t oi = ((size_t)(batch * NO + o) << 14) + plocal;
        if (isf32) {
            *(float4*)((float*)out + oi) = gv;
        } else {
            uint_t p0 = (uint_t)f2bf(gv.x) | ((uint_t)f2bf(gv.y) << 16);
            uint_t p1 = (uint_t)f2bf(gv.z) | ((uint_t)f2bf(gv.w) << 16);
            *(uint2*)((ushort_t*)out + oi) = make_uint2(p0, p1);
        }
    }
}

// ---------------------------------------------------------------------------
extern "C" void kernel_launch(void* const* d_in, const int* in_sizes, int n_in,
                              void* d_out, int out_size, void* d_ws, size_t ws_size,
                              hipStream_t stream) {
    const void* x      = d_in[0];
    const void* w1     = d_in[1];
    const void* b1     = d_in[2];
    const void* w2     = d_in[3];
    const void* b2     = d_in[4];
    const void* ln1w   = d_in[5];
    const void* ln1b   = d_in[6];
    const void* conv_w = d_in[7];
    const void* ln2w   = d_in[8];
    const void* ln2b   = d_in[9];
    const void* map_w  = d_in[10];
    const void* map_b  = d_in[11];
    const void* ln3w   = d_in[12];
    const void* ln3b   = d_in[13];

    char* ws = (char*)d_ws;
    ushort_t* xT    = (ushort_t*)(ws);                  // 16,777,216 B
    ushort_t* y1    = (ushort_t*)(ws + 16777216);       // 16,777,216 B
    ushort_t* wfrag = (ushort_t*)(ws + 33554432);       // 131,072 B
    ushort_t* w1b   = (ushort_t*)(ws + 33685504);       //   8,192 B
    ushort_t* w2b   = (ushort_t*)(ws + 33693696);       //  25,600 B
    float*    b1f   = (float*)(ws + 33719296);
    float*    b2f   = (float*)(ws + 33719424);
    float*    ln1wf = (float*)(ws + 33721024);
    float*    ln1bf = (float*)(ws + 33721536);
    float*    mbf   = (float*)(ws + 33722048);
    float*    ln2wf = (float*)(ws + 33723072);
    float*    ln2bf = (float*)(ws + 33724096);
    float*    ln3wf = (float*)(ws + 33725120);
    float*    ln3bf = (float*)(ws + 33726144);
    int*      flag  = (int*)(ws + 33727168);
    const size_t NEED_SMALL = 33727184;
    ushort_t* wkT   = (ushort_t*)(ws + 33727232);       // 52,428,800 B
    const size_t NEED_BIG = 33727232 + (size_t)NKP * NPIX * 2;   // ~86.2 MB

    if (ws_size < NEED_SMALL) {
        int nwords = out_size / 2;
        ksentinel<<<(nwords + 255) / 256, 256, 0, stream>>>((uint_t*)d_out, nwords);
        return;
    }

    kdetect<<<1, 64, 0, stream>>>((const uint_t*)x, flag);
    kprep<<<128, 256, 0, stream>>>(w1, w2, b1, b2, ln1w, ln1b,
                                   ln2w, ln2b, map_b, ln3w, ln3b, flag,
                                   w1b, w2b, b1f, b2f, ln1wf, ln1bf,
                                   ln2wf, ln2bf, mbf, ln3wf, ln3bf);
    kfrag<<<32, 256, 0, stream>>>(conv_w, map_w, flag, wfrag);
    ktrans<<<dim3(8, 128, 4), 256, 0, stream>>>(x, xT, flag);

    if (ws_size >= NEED_BIG) {
        k1a<<<1024, 256, 0, stream>>>(xT, w1b, b1f, w2b, b2f, wkT);
        k1b<<<1024, 512, 0, stream>>>(xT, wkT, ln1wf, ln1bf, y1);
    } else {
        k1_fused<<<dim3(16, 64, 4), 64, 0, stream>>>(xT, w1b, b1f, w2b, b2f,
                                                     ln1wf, ln1bf, y1);
    }

    k23<<<NPIX / 32, 256, 0, stream>>>(y1, xT, wfrag, mbf,
                                       ln2wf, ln2bf, ln3wf, ln3bf, d_out, flag);
}

// Round 7
// 222.906 us; speedup vs baseline: 1.4887x; 1.0251x over previous
//
#include <hip/hip_runtime.h>

typedef unsigned short ushort_t;
typedef unsigned int uint_t;

#define NB 4
#define NC 128
#define NH 128
#define NW 128
#define NPIX 65536   // NB*NH*NW
#define NMID 32
#define NKK 49
#define NK 392
#define NKP 400      // NK padded to 25 n-tiles of 16
#define NO 256
#define LN_EPS 1e-6f

typedef __attribute__((ext_vector_type(8))) short short8;
typedef __attribute__((ext_vector_type(4))) float floatx4;

__device__ __forceinline__ float bf2f(ushort_t u) {
    union { uint_t i; float f; } v; v.i = ((uint_t)u) << 16; return v.f;
}
__device__ __forceinline__ float bf2f_lo(uint_t u) {
    union { uint_t i; float f; } v; v.i = u << 16; return v.f;
}
__device__ __forceinline__ float bf2f_hi(uint_t u) {
    union { uint_t i; float f; } v; v.i = u & 0xffff0000u; return v.f;
}
__device__ __forceinline__ ushort_t f2bf(float f) {
    union { float f; uint_t i; } v; v.f = f;
    uint_t x = v.i;
    uint_t r = (x + 0x7FFFu + ((x >> 16) & 1u)) >> 16;
    return (ushort_t)r;
}
__device__ __forceinline__ float gelu_f(float x) {
    return 0.5f * x * (1.0f + erff(x * 0.70710678118654752f));
}
__device__ __forceinline__ float ldin(const void* p, int i, int isf32) {
    return isf32 ? ((const float*)p)[i] : bf2f(((const ushort_t*)p)[i]);
}
// global -> LDS direct DMA, 16B per lane; LDS dest = uniform base + lane*16
__device__ __forceinline__ void gload_lds16(const void* g, void* l) {
    __builtin_amdgcn_global_load_lds(
        (const __attribute__((address_space(1))) void*)g,
        (__attribute__((address_space(3))) void*)l, 16, 0, 0);
}

// ---------------------------------------------------------------------------
__global__ void kdetect(const uint_t* __restrict__ xw, int* __restrict__ flag) {
    int lane = threadIdx.x;
    int cnt = 0;
    for (int j = 0; j < 8; j++) {
        uint_t w = xw[lane * 8 + j];
        uint_t e = (w >> 7) & 0xffu;
        if (e >= 110u && e <= 135u) cnt++;
    }
    for (int d = 1; d < 64; d <<= 1) cnt += __shfl_xor(cnt, d);
    if (lane == 0) flag[0] = (cnt < 256) ? 1 : 0;
}

__global__ void ksentinel(uint_t* __restrict__ out, int nwords) {
    int i = blockIdx.x * 256 + threadIdx.x;
    if (i < nwords) out[i] = 0x40004000u;
}

// ---------------------------------------------------------------------------
// K0a: transpose x (B,C,H,W) -> xT (B,H,W,C) canonical bf16.
// ---------------------------------------------------------------------------
__global__ __launch_bounds__(256) void ktrans(const void* __restrict__ x,
                                              ushort_t* __restrict__ xT,
                                              const int* __restrict__ flag) {
    int isf32 = flag[0];
    int b = blockIdx.z, h = blockIdx.y;
    int wchunk = blockIdx.x & 1, cchunk = blockIdx.x >> 1;
    int w0 = wchunk << 6, c0 = cchunk << 5;
    __shared__ ushort_t tile[32][66];
    int tx = threadIdx.x & 63, ty = threadIdx.x >> 6;
    for (int r = 0; r < 32; r += 4) {
        int idx = (((b * NC + c0 + r + ty) * NH) + h) * NW + w0 + tx;
        tile[r + ty][tx] = isf32 ? f2bf(((const float*)x)[idx])
                                 : ((const ushort_t*)x)[idx];
    }
    __syncthreads();
    int cc = threadIdx.x & 31, wq = threadIdx.x >> 5;
    for (int pp = 0; pp < 64; pp += 8) {
        int wx = pp + wq;
        xT[((size_t)((b * NH + h) * NW) + w0 + wx) * NC + c0 + cc] = tile[cc][wx];
    }
}

// ---------------------------------------------------------------------------
// K0b: param prep (w1b/w2b for k1a; small vectors -> fp32).
// ---------------------------------------------------------------------------
__global__ __launch_bounds__(256) void kprep(const void* w1, const void* w2,
                                             const void* b1, const void* b2,
                                             const void* ln1w, const void* ln1b,
                                             const void* ln2w, const void* ln2b,
                                             const void* map_b,
                                             const void* ln3w, const void* ln3b,
                                             const int* __restrict__ flag,
                                             ushort_t* __restrict__ w1b,
                                             ushort_t* __restrict__ w2b,
                                             float* __restrict__ b1f,
                                             float* __restrict__ b2f,
                                             float* __restrict__ ln1wf,
                                             float* __restrict__ ln1bf,
                                             float* __restrict__ ln2wf,
                                             float* __restrict__ ln2bf,
                                             float* __restrict__ mbf,
                                             float* __restrict__ ln3wf,
                                             float* __restrict__ ln3bf) {
    int isf32 = flag[0];
    int i = blockIdx.x * 256 + threadIdx.x;
    if (i < NMID * NC) w1b[i] = f2bf(ldin(w1, i, isf32));
    if (i < NKP * NMID) w2b[i] = (i < NK * NMID) ? f2bf(ldin(w2, i, isf32))
                                                 : (ushort_t)0;
    if (i < NMID) b1f[i] = ldin(b1, i, isf32);
    if (i < NKP)  b2f[i] = (i < NK) ? ldin(b2, i, isf32) : 0.f;
    if (i < NC) { ln1wf[i] = ldin(ln1w, i, isf32); ln1bf[i] = ldin(ln1b, i, isf32); }
    if (i < NO) {
        ln2wf[i] = ldin(ln2w, i, isf32); ln2bf[i] = ldin(ln2b, i, isf32);
        mbf[i]   = ldin(map_b, i, isf32);
        ln3wf[i] = ldin(ln3w, i, isf32); ln3bf[i] = ldin(ln3b, i, isf32);
    }
}

// ---------------------------------------------------------------------------
// KFRAG: repack conv_w/map_w into k-block-major MFMA-fragment order for k23:
// chunk id cid = [kb:2][br:1][n4:4][lane:6], chunk = 8 bf16 = 16 B.
// Each kb-tile (2048 chunks = 32 KB) is CONTIGUOUS -> linear global_load_lds
// target in k23. o = n4*16 + (lane&15), ch = kb*32 + (lane>>4)*8 .. +8.
// grid 32 x 256.
// ---------------------------------------------------------------------------
__global__ __launch_bounds__(256) void kfrag(const void* conv_w, const void* map_w,
                                             const int* __restrict__ flag,
                                             ushort_t* __restrict__ wfrag) {
    int isf32 = flag[0];
    int cid = blockIdx.x * 256 + threadIdx.x;   // [0, 8192)
    int lane = cid & 63, n4 = (cid >> 6) & 15, br = (cid >> 10) & 1, kb = cid >> 11;
    int o = n4 * 16 + (lane & 15);
    int ch0 = kb * 32 + (lane >> 4) * 8;
    const void* src = br ? map_w : conv_w;
    ushort_t* dst = wfrag + (size_t)cid * 8;
#pragma unroll
    for (int j = 0; j < 8; j++)
        dst[j] = f2bf(ldin(src, o * NC + ch0 + j, isf32));
}

// ---------------------------------------------------------------------------
// K1a: wk producer (unchanged). grid 1024, block 256.
// ---------------------------------------------------------------------------
__global__ __launch_bounds__(256) void k1a(const ushort_t* __restrict__ xT,
                                           const ushort_t* __restrict__ w1b,
                                           const float* __restrict__ b1f,
                                           const ushort_t* __restrict__ w2b,
                                           const float* __restrict__ b2f,
                                           ushort_t* __restrict__ wkT) {
    __shared__ ushort_t midbuf[64 * 32];
    __shared__ ushort_t wkstage[NKP * 66];

    int t = threadIdx.x;
    int lane = t & 63;
    int w = __builtin_amdgcn_readfirstlane(t >> 6);
    int l16 = lane & 15, quad = lane >> 4;
    int tileid = blockIdx.x;
    int tilex = tileid & 15, tiley = (tileid >> 4) & 15, b = tileid >> 8;
    int h0 = tiley * 8, w0 = tilex * 8;

    int lpx_a = 16 * w + l16;
    int py = lpx_a >> 3, pxx = lpx_a & 7;
    const ushort_t* abase = xT + (size_t)((b * NH + h0 + py) * NW + w0 + pxx) * NC + quad * 8;
    floatx4 am0 = (floatx4)0.f, am1 = (floatx4)0.f;
#pragma unroll
    for (int kb = 0; kb < 4; kb++) {
        short8 a   = *(const short8*)(abase + kb * 32);
        short8 b0  = *(const short8*)(w1b + (l16) * NC + kb * 32 + quad * 8);
        short8 b1v = *(const short8*)(w1b + (16 + l16) * NC + kb * 32 + quad * 8);
        am0 = __builtin_amdgcn_mfma_f32_16x16x32_bf16(a, b0, am0, 0, 0, 0);
        am1 = __builtin_amdgcn_mfma_f32_16x16x32_bf16(a, b1v, am1, 0, 0, 0);
    }
    {
        float bia0 = b1f[l16], bia1 = b1f[16 + l16];
#pragma unroll
        for (int r = 0; r < 4; r++) {
            int m = 16 * w + quad * 4 + r;
            midbuf[m * 32 + l16]      = f2bf(fmaxf(am0[r] + bia0, 0.f));
            midbuf[m * 32 + 16 + l16] = f2bf(fmaxf(am1[r] + bia1, 0.f));
        }
    }
    __syncthreads();

    short8 aM = *(const short8*)(midbuf + (16 * w + l16) * 32 + quad * 8);
#pragma unroll
    for (int nt = 0; nt < 25; nt++) {
        int n = nt * 16 + l16;
        short8 bw = *(const short8*)(w2b + n * 32 + quad * 8);
        floatx4 c = __builtin_amdgcn_mfma_f32_16x16x32_bf16(aM, bw, (floatx4)0.f, 0, 0, 0);
        float bias = b2f[n];
#pragma unroll
        for (int r = 0; r < 4; r++)
            wkstage[n * 66 + 16 * w + quad * 4 + r] = f2bf(c[r] + bias);
    }
    __syncthreads();

    int krow = t >> 5, px2 = t & 31;
    for (int it = 0; it < 50; it++) {
        int k = it * 8 + krow;
        uint_t v = *(const uint_t*)&wkstage[k * 66 + 2 * px2];
        *(uint_t*)&wkT[(size_t)k * NPIX + tileid * 64 + 2 * px2] = v;
    }
}

// ---------------------------------------------------------------------------
// K1b v3 (unchanged from round 8). grid 1024, block 512.
// ---------------------------------------------------------------------------
__global__ __launch_bounds__(512) void k1b(const ushort_t* __restrict__ xT,
                                           const ushort_t* __restrict__ wkT,
                                           const float* __restrict__ ln1wf,
                                           const float* __restrict__ ln1bf,
                                           ushort_t* __restrict__ y1) {
    __shared__ __align__(16) char smem[50432];
    uint4* x8   = (uint4*)smem;
    float* sred = (float*)smem;

    int t = threadIdx.x;
    int lane = t & 63;
    int w = __builtin_amdgcn_readfirstlane(t >> 6);
    int tileid = blockIdx.x;
    int tilex = tileid & 15, tiley = (tileid >> 4) & 15, b = tileid >> 8;
    int h0 = tiley * 8, w0 = tilex * 8;
    int py = lane >> 3, pxx = lane & 7;

    const ushort_t* wkbase = wkT + (size_t)(w * NKK) * NPIX + tileid * 64 + lane;
    uint_t wkp[25];
#pragma unroll
    for (int j = 0; j < 24; j++) {
        uint_t lo = wkbase[(size_t)(2 * j) * NPIX];
        uint_t hi = wkbase[(size_t)(2 * j + 1) * NPIX];
        wkp[j] = lo | (hi << 16);
    }
    wkp[24] = wkbase[(size_t)48 * NPIX];

    for (int it = 0; it < 7; it++) {
        int idx = it * 512 + t;
        if (idx < 3136) {
            int oct = idx & 15, hp = idx >> 4;
            int hy = hp / 14, hx = hp - hy * 14;
            int gh = h0 + hy - 3, gw = w0 + hx - 3;
            uint4 v = make_uint4(0u, 0u, 0u, 0u);
            if ((unsigned)gh < (unsigned)NH && (unsigned)gw < (unsigned)NW) {
                v = *(const uint4*)&xT[(size_t)((b * NH + gh) * NW + gw) * NC + 8 * oct];
            }
            x8[oct * 197 + hp] = v;
        }
    }
    __syncthreads();

    int base0 = py * 14 + pxx;
    float a[16];
#pragma unroll
    for (int j = 0; j < 16; j++) a[j] = 0.f;

#pragma unroll
    for (int tap = 0; tap < NKK; tap++) {
        float wkf = (tap & 1) ? bf2f((ushort_t)(wkp[tap >> 1] >> 16))
                              : bf2f((ushort_t)(wkp[tap >> 1] & 0xffffu));
        int xa = base0 + (tap / 7) * 14 + (tap % 7);
        uint4 u0 = x8[(2 * w) * 197 + xa];
        uint4 u1 = x8[(2 * w + 1) * 197 + xa];
        a[0]  = fmaf(wkf, bf2f_lo(u0.x), a[0]);
        a[1]  = fmaf(wkf, bf2f_hi(u0.x), a[1]);
        a[2]  = fmaf(wkf, bf2f_lo(u0.y), a[2]);
        a[3]  = fmaf(wkf, bf2f_hi(u0.y), a[3]);
        a[4]  = fmaf(wkf, bf2f_lo(u0.z), a[4]);
        a[5]  = fmaf(wkf, bf2f_hi(u0.z), a[5]);
        a[6]  = fmaf(wkf, bf2f_lo(u0.w), a[6]);
        a[7]  = fmaf(wkf, bf2f_hi(u0.w), a[7]);
        a[8]  = fmaf(wkf, bf2f_lo(u1.x), a[8]);
        a[9]  = fmaf(wkf, bf2f_hi(u1.x), a[9]);
        a[10] = fmaf(wkf, bf2f_lo(u1.y), a[10]);
        a[11] = fmaf(wkf, bf2f_hi(u1.y), a[11]);
        a[12] = fmaf(wkf, bf2f_lo(u1.z), a[12]);
        a[13] = fmaf(wkf, bf2f_hi(u1.z), a[13]);
        a[14] = fmaf(wkf, bf2f_lo(u1.w), a[14]);
        a[15] = fmaf(wkf, bf2f_hi(u1.w), a[15]);
    }
    __syncthreads();

    float s = 0.f, sq = 0.f;
#pragma unroll
    for (int j = 0; j < 16; j++) { s += a[j]; sq += a[j] * a[j]; }
    sred[(w * 64 + lane) * 2]     = s;
    sred[(w * 64 + lane) * 2 + 1] = sq;
    __syncthreads();
    float ts = 0.f, tq = 0.f;
#pragma unroll
    for (int r = 0; r < 8; r++) {
        ts += sred[(r * 64 + lane) * 2];
        tq += sred[(r * 64 + lane) * 2 + 1];
    }
    float mean = ts * (1.0f / NC);
    float var = tq * (1.0f / NC) - mean * mean;
    float rstd = rsqrtf(var + LN_EPS);

    int p = (b * NH + h0 + py) * NW + w0 + pxx;
    uint_t pk[8];
#pragma unroll
    for (int j = 0; j < 8; j++) {
        int c0 = 16 * w + 2 * j;
        float g0 = gelu_f((a[2 * j] - mean) * rstd * ln1wf[c0] + ln1bf[c0]);
        float g1 = gelu_f((a[2 * j + 1] - mean) * rstd * ln1wf[c0 + 1] + ln1bf[c0 + 1]);
        pk[j] = (uint_t)f2bf(g0) | ((uint_t)f2bf(g1) << 16);
    }
    uint4* dst = (uint4*)(y1 + (size_t)p * NC + 16 * w);
    dst[0] = make_uint4(pk[0], pk[1], pk[2], pk[3]);
    dst[1] = make_uint4(pk[4], pk[5], pk[6], pk[7]);
}

// ---------------------------------------------------------------------------
// K1 fused fallback — used only if ws too small for wkT.
// ---------------------------------------------------------------------------
__global__ __launch_bounds__(64) void k1_fused(const ushort_t* __restrict__ xT,
                                               const ushort_t* __restrict__ w1b,
                                               const float* __restrict__ b1f,
                                               const ushort_t* __restrict__ w2b,
                                               const float* __restrict__ b2f,
                                               const float* __restrict__ ln1wf,
                                               const float* __restrict__ ln1bf,
                                               ushort_t* __restrict__ y1) {
    __shared__ ushort_t midbuf[16 * 32];
    __shared__ ushort_t wkbuf[16 * NKP];

    int lane = threadIdx.x;
    int l16 = lane & 15, quad = lane >> 4;
    int b = blockIdx.z;
    int h0 = blockIdx.y * 2, w0 = blockIdx.x * 8;

    int Pa = (b * NH + h0 + (l16 >> 3)) * NW + w0 + (l16 & 7);
    const ushort_t* abase = xT + (size_t)Pa * NC + quad * 8;
    floatx4 am0 = (floatx4)0.f, am1 = (floatx4)0.f;
#pragma unroll
    for (int kb = 0; kb < 4; kb++) {
        short8 a   = *(const short8*)(abase + kb * 32);
        short8 b0  = *(const short8*)(w1b + (l16) * NC + kb * 32 + quad * 8);
        short8 b1v = *(const short8*)(w1b + (16 + l16) * NC + kb * 32 + quad * 8);
        am0 = __builtin_amdgcn_mfma_f32_16x16x32_bf16(a, b0, am0, 0, 0, 0);
        am1 = __builtin_amdgcn_mfma_f32_16x16x32_bf16(a, b1v, am1, 0, 0, 0);
    }
    {
        float bia0 = b1f[l16], bia1 = b1f[16 + l16];
#pragma unroll
        for (int r = 0; r < 4; r++) {
            int m = quad * 4 + r;
            midbuf[m * 32 + l16]      = f2bf(fmaxf(am0[r] + bia0, 0.f));
            midbuf[m * 32 + 16 + l16] = f2bf(fmaxf(am1[r] + bia1, 0.f));
        }
    }
    __syncthreads();

    short8 aM = *(const short8*)(midbuf + l16 * 32 + quad * 8);
#pragma unroll
    for (int nt = 0; nt < 25; nt++) {
        int n = nt * 16 + l16;
        short8 bw = *(const short8*)(w2b + n * 32 + quad * 8);
        floatx4 c = __builtin_amdgcn_mfma_f32_16x16x32_bf16(aM, bw, (floatx4)0.f, 0, 0, 0);
        float bias = b2f[n];
#pragma unroll
        for (int r = 0; r < 4; r++)
            wkbuf[(quad * 4 + r) * NKP + n] = f2bf(c[r] + bias);
    }
    __syncthreads();

    int g = lane >> 3;
    float l1w0 = ln1wf[2 * lane], l1w1 = ln1wf[2 * lane + 1];
    float l1b0 = ln1bf[2 * lane], l1b1 = ln1bf[2 * lane + 1];

    for (int i = 0; i < 16; i++) {
        int hh0 = h0 + (i >> 3), ww0 = w0 + (i & 7);
        int p = (b * NH + hh0) * NW + ww0;
        const ushort_t* wkrow = wkbuf + i * NKP + g * NKK;
        float a0 = 0.f, a1 = 0.f;
#pragma unroll
        for (int dy = -3; dy <= 3; dy++) {
            int hh = hh0 + dy;
            if ((unsigned)hh >= (unsigned)NH) continue;
#pragma unroll
            for (int dx = -3; dx <= 3; dx++) {
                int ww = ww0 + dx;
                if ((unsigned)ww >= (unsigned)NW) continue;
                float wkv = bf2f(wkrow[(dy + 3) * 7 + (dx + 3)]);
                uint_t xp = *(const uint_t*)(xT + ((size_t)(p + dy * NW + dx)) * NC + 2 * lane);
                a0 = fmaf(wkv, bf2f((ushort_t)(xp & 0xffffu)), a0);
                a1 = fmaf(wkv, bf2f((ushort_t)(xp >> 16)), a1);
            }
        }
        float s = a0 + a1, sq = a0 * a0 + a1 * a1;
#pragma unroll
        for (int d = 1; d < 64; d <<= 1) {
            s  += __shfl_xor(s, d);
            sq += __shfl_xor(sq, d);
        }
        float mean = s * (1.0f / NC);
        float var = sq * (1.0f / NC) - mean * mean;
        float rstd = rsqrtf(var + LN_EPS);
        float g0 = gelu_f((a0 - mean) * rstd * l1w0 + l1b0);
        float g1 = gelu_f((a1 - mean) * rstd * l1w1 + l1b1);
        uint_t pk = (uint_t)f2bf(g0) | ((uint_t)f2bf(g1) << 16);
        *(uint_t*)(y1 + (size_t)p * NC + 2 * lane) = pk;
    }
}

// ---------------------------------------------------------------------------
// K23 v10: v9 with the occupancy cap raised. Post-mortem r6: v9's natural
// allocation is exactly 64 VGPR + 64 AGPR = 128 regs/lane under the LOOSER
// (256,3) budget -> the (256,4) 128-reg budget is already met with no
// restructuring. r3's spill came from v7's fat epilogue (needed ~110 arch
// VGPRs under a 64-VGPR ceiling); v9's streaming epilogue needs 64 exactly.
// One line changed: min-waves 3 -> 4 (4 waves/SIMD, 16 waves/CU; LDS 32KB
// allows 5 blocks/CU so regs are the binding limit). Falsifiable no-spill
// check: WRITE_SIZE must stay 65.5 MB and VGPR_Count 64.
// grid 2048, block 256.
// ---------------------------------------------------------------------------
__global__ __launch_bounds__(256, 4) void k23(const ushort_t* __restrict__ y1,
                                              const ushort_t* __restrict__ xT,
                                              const ushort_t* __restrict__ wfrag,
                                              const float* __restrict__ mbf,
                                              const float* __restrict__ ln2wf,
                                              const float* __restrict__ ln2bf,
                                              const float* __restrict__ ln3wf,
                                              const float* __restrict__ ln3bf,
                                              void* __restrict__ out,
                                              const int* __restrict__ flag) {
    __shared__ __align__(16) char sbuf[32768];   // B stage, reused for stats

    int isf32 = flag[0];
    int t = threadIdx.x;
    int lane = t & 63;
    int w = __builtin_amdgcn_readfirstlane(t >> 6);   // 0..3
    int quad = lane >> 4, l16 = lane & 15;
    int pair = w >> 1;                                // 0..1 -> px group
    int oh   = w & 1;                                 // 0..1 -> o-half (128 o's)

    int P0 = blockIdx.x * 32;
    int pw = P0 + pair * 16;                          // this wave's first pixel
    const ushort_t* aYp = y1 + (size_t)(pw + l16) * NC + quad * 8;
    const ushort_t* aXp = xT + (size_t)(pw + l16) * NC + quad * 8;

    // stage kb=0 B-tile (32KB): wave w covers chunks [w*512, w*512+512)
    {
        const ushort_t* gsrc = wfrag + (size_t)(w * 512 + lane) * 8;
        char* ldst = sbuf + (size_t)(w * 512) * 16;
#pragma unroll
        for (int i = 0; i < 8; i++)
            gload_lds16(gsrc + i * 64 * 8, ldst + i * 64 * 16);
    }
    // A operands (both branches) for all 4 k-blocks, hoisted to registers
    short8 Ay[4], Ax[4];
#pragma unroll
    for (int kb = 0; kb < 4; kb++) {
        Ay[kb] = *(const short8*)(aYp + kb * 32);
        Ax[kb] = *(const short8*)(aXp + kb * 32);
    }
    __syncthreads();

    floatx4 accC[8], accM[8];
#pragma unroll
    for (int j = 0; j < 8; j++) { accC[j] = (floatx4)0.f; accM[j] = (floatx4)0.f; }

#pragma unroll
    for (int kb = 0; kb < 4; kb++) {
        short8 ay = Ay[kb], ax = Ax[kb];
#pragma unroll
        for (int j = 0; j < 8; j++) {
            int n4 = oh * 8 + j;
            // tile layout: [br:1][n4:4][lane:6] chunks of 16 B
            short8 bc = *(const short8*)(sbuf + (size_t)(n4 * 64 + lane) * 16);
            short8 bm = *(const short8*)(sbuf + 16384 + (size_t)(n4 * 64 + lane) * 16);
            accC[j] = __builtin_amdgcn_mfma_f32_16x16x32_bf16(ay, bc, accC[j], 0, 0, 0);
            accM[j] = __builtin_amdgcn_mfma_f32_16x16x32_bf16(ax, bm, accM[j], 0, 0, 0);
        }
        __syncthreads();                              // all B reads done
        if (kb < 3) {
            const ushort_t* gsrc = wfrag + ((size_t)(kb + 1) * 2048 + w * 512 + lane) * 8;
            char* ldst = sbuf + (size_t)(w * 512) * 16;
#pragma unroll
            for (int i = 0; i < 8; i++)
                gload_lds16(gsrc + i * 64 * 8, ldst + i * 64 * 16);
            __syncthreads();                          // staging visible (vmcnt drained)
        }
    }

    // map-branch bias (before LN3 stats)
#pragma unroll
    for (int j = 0; j < 8; j++) {
        float mb = mbf[(oh * 8 + j) * 16 + l16];
#pragma unroll
        for (int r = 0; r < 4; r++) accM[j][r] += mb;
    }

    // LN partial stats per px (px = quad*4 + r) over this wave's 128 o's:
    // accumulate over 8 n4, butterfly over the 16 o-lanes (d<16 stays inside
    // each l16 group).
    floatx4 s1 = (floatx4)0.f, q1 = (floatx4)0.f, s2 = (floatx4)0.f, q2 = (floatx4)0.f;
#pragma unroll
    for (int j = 0; j < 8; j++)
#pragma unroll
        for (int r = 0; r < 4; r++) {
            float a = accC[j][r], m = accM[j][r];
            s1[r] += a; q1[r] += a * a;
            s2[r] += m; q2[r] += m * m;
        }
#pragma unroll
    for (int d = 1; d < 16; d <<= 1) {
#pragma unroll
        for (int r = 0; r < 4; r++) {
            s1[r] += __shfl_xor(s1[r], d);
            q1[r] += __shfl_xor(q1[r], d);
            s2[r] += __shfl_xor(s2[r], d);
            q2[r] += __shfl_xor(q2[r], d);
        }
    }

    // exchange partial stats with the pair's other o-half through sbuf (dead):
    // layout [pair:1][oh:1][px:4bits][4 stats] floats = 256 floats = 1 KB.
    float* sstat = (float*)sbuf;
    if (l16 == 0) {
#pragma unroll
        for (int r = 0; r < 4; r++) {
            float* sp = sstat + (((pair * 2 + oh) * 16) + quad * 4 + r) * 4;
            sp[0] = s1[r]; sp[1] = q1[r]; sp[2] = s2[r]; sp[3] = q2[r];
        }
    }
    __syncthreads();

    floatx4 mn1, rs1, mn2, rs2;
#pragma unroll
    for (int r = 0; r < 4; r++) {
        const float* op = sstat + (((pair * 2 + (oh ^ 1)) * 16) + quad * 4 + r) * 4;
        float S1 = s1[r] + op[0], Q1 = q1[r] + op[1];
        float S2 = s2[r] + op[2], Q2 = q2[r] + op[3];
        mn1[r] = S1 * (1.0f / NO);
        rs1[r] = rsqrtf(Q1 * (1.0f / NO) - mn1[r] * mn1[r] + LN_EPS);
        mn2[r] = S2 * (1.0f / NO);
        rs2[r] = rsqrtf(Q2 * (1.0f / NO) - mn2[r] * mn2[r] + LN_EPS);
    }

    // streaming epilogue: per n4, normalize both branches, gelu, direct store
    // (lane's 4 acc components are 4 CONTIGUOUS pixels -> float4/uint2).
    int batch = pw >> 14;
    int plocal = (pw & 16383) + quad * 4;
#pragma unroll
    for (int j = 0; j < 8; j++) {
        int o = (oh * 8 + j) * 16 + l16;
        float l2w = ln2wf[o], l2b = ln2bf[o];
        float l3w = ln3wf[o], l3b = ln3bf[o];
        float4 gv;
        {
            float v1, v2;
            v1 = (accC[j][0] - mn1[0]) * rs1[0] * l2w + l2b;
            v2 = (accM[j][0] - mn2[0]) * rs2[0] * l3w + l3b;
            gv.x = gelu_f(v1 + v2);
            v1 = (accC[j][1] - mn1[1]) * rs1[1] * l2w + l2b;
            v2 = (accM[j][1] - mn2[1]) * rs2[1] * l3w + l3b;
            gv.y = gelu_f(v1 + v2);
            v1 = (accC[j][2] - mn1[2]) * rs1[2] * l2w + l2b;
            v2 = (accM[j][2] - mn2[2]) * rs2[2] * l3w + l3b;
            gv.z = gelu_f(v1 + v2);
            v1 = (accC[j][3] - mn1[3]) * rs1[3] * l2w + l2b;
            v2 = (accM[j][3] - mn2[3]) * rs2[3] * l3w + l3b;
            gv.w = gelu_f(v1 + v2);
        }
        size_t oi = ((size_t)(batch * NO + o) << 14) + plocal;
        if (isf32) {
            *(float4*)((float*)out + oi) = gv;
        } else {
            uint_t p0 = (uint_t)f2bf(gv.x) | ((uint_t)f2bf(gv.y) << 16);
            uint_t p1 = (uint_t)f2bf(gv.z) | ((uint_t)f2bf(gv.w) << 16);
            *(uint2*)((ushort_t*)out + oi) = make_uint2(p0, p1);
        }
    }
}

// ---------------------------------------------------------------------------
extern "C" void kernel_launch(void* const* d_in, const int* in_sizes, int n_in,
                              void* d_out, int out_size, void* d_ws, size_t ws_size,
                              hipStream_t stream) {
    const void* x      = d_in[0];
    const void* w1     = d_in[1];
    const void* b1     = d_in[2];
    const void* w2     = d_in[3];
    const void* b2     = d_in[4];
    const void* ln1w   = d_in[5];
    const void* ln1b   = d_in[6];
    const void* conv_w = d_in[7];
    const void* ln2w   = d_in[8];
    const void* ln2b   = d_in[9];
    const void* map_w  = d_in[10];
    const void* map_b  = d_in[11];
    const void* ln3w   = d_in[12];
    const void* ln3b   = d_in[13];

    char* ws = (char*)d_ws;
    ushort_t* xT    = (ushort_t*)(ws);                  // 16,777,216 B
    ushort_t* y1    = (ushort_t*)(ws + 16777216);       // 16,777,216 B
    ushort_t* wfrag = (ushort_t*)(ws + 33554432);       // 131,072 B
    ushort_t* w1b   = (ushort_t*)(ws + 33685504);       //   8,192 B
    ushort_t* w2b   = (ushort_t*)(ws + 33693696);       //  25,600 B
    float*    b1f   = (float*)(ws + 33719296);
    float*    b2f   = (float*)(ws + 33719424);
    float*    ln1wf = (float*)(ws + 33721024);
    float*    ln1bf = (float*)(ws + 33721536);
    float*    mbf   = (float*)(ws + 33722048);
    float*    ln2wf = (float*)(ws + 33723072);
    float*    ln2bf = (float*)(ws + 33724096);
    float*    ln3wf = (float*)(ws + 33725120);
    float*    ln3bf = (float*)(ws + 33726144);
    int*      flag  = (int*)(ws + 33727168);
    const size_t NEED_SMALL = 33727184;
    ushort_t* wkT   = (ushort_t*)(ws + 33727232);       // 52,428,800 B
    const size_t NEED_BIG = 33727232 + (size_t)NKP * NPIX * 2;   // ~86.2 MB

    if (ws_size < NEED_SMALL) {
        int nwords = out_size / 2;
        ksentinel<<<(nwords + 255) / 256, 256, 0, stream>>>((uint_t*)d_out, nwords);
        return;
    }

    kdetect<<<1, 64, 0, stream>>>((const uint_t*)x, flag);
    kprep<<<128, 256, 0, stream>>>(w1, w2, b1, b2, ln1w, ln1b,
                                   ln2w, ln2b, map_b, ln3w, ln3b, flag,
                                   w1b, w2b, b1f, b2f, ln1wf, ln1bf,
                                   ln2wf, ln2bf, mbf, ln3wf, ln3bf);
    kfrag<<<32, 256, 0, stream>>>(conv_w, map_w, flag, wfrag);
    ktrans<<<dim3(8, 128, 4), 256, 0, stream>>>(x, xT, flag);

    if (ws_size >= NEED_BIG) {
        k1a<<<1024, 256, 0, stream>>>(xT, w1b, b1f, w2b, b2f, wkT);
        k1b<<<1024, 512, 0, stream>>>(xT, wkT, ln1wf, ln1bf, y1);
    } else {
        k1_fused<<<dim3(16, 64, 4), 64, 0, stream>>>(xT, w1b, b1f, w2b, b2f,
                                                     ln1wf, ln1bf, y1);
    }

    k23<<<NPIX / 32, 256, 0, stream>>>(y1, xT, wfrag, mbf,
                                       ln2wf, ln2bf, ln3wf, ln3bf, d_out, flag);
}